// Round 3
// baseline (504.861 us; speedup 1.0000x reference)
//
#include <hip/hip_runtime.h>

#define B_   1024
#define A_   64
#define G_   31
#define W_   8
#define H_   512
#define L_   2
#define S_   32
#define DK_  32
#define K3H_ 1536

typedef short short8 __attribute__((ext_vector_type(8)));
typedef float floatx4 __attribute__((ext_vector_type(4)));

__device__ __forceinline__ float bf2f(unsigned short u){
  union { unsigned int i; float f; } x; x.i = ((unsigned int)u) << 16; return x.f;
}
__device__ __forceinline__ unsigned short f2bf(float f){
  union { float f; unsigned int i; } x; x.f = f;
  unsigned int u = x.i;
  return (unsigned short)((u + 0x7FFFu + ((u >> 16) & 1u)) >> 16);
}
__device__ __forceinline__ void gl_lds16(const unsigned short* g, unsigned short* l){
  __builtin_amdgcn_global_load_lds((const __attribute__((address_space(1))) unsigned int*)g,
                                   (__attribute__((address_space(3))) unsigned int*)l, 16, 0, 0);
}

// ---------------- K0a: LDS-tiled transpose+convert for lr_w and lin_w ----------------
__global__ __launch_bounds__(256) void prep_transpose(
    const float* __restrict__ lr_w, const float* __restrict__ lin_w,
    unsigned short* __restrict__ lr_wT, unsigned short* __restrict__ lin_wT){
  __shared__ float tile[64][65];
  int bx = blockIdx.x;
  const float* src; unsigned short* dst; int R, C;
  if (bx < 192){ src = lr_w;  dst = lr_wT;  R = 1536; C = 512; }
  else         { bx -= 192; src = lin_w; dst = lin_wT; R = 512;  C = 512; }
  int rt = bx >> 3, ct = bx & 7;
  int tid = threadIdx.x;
  int r16 = tid >> 4, c4 = tid & 15;
  #pragma unroll
  for (int p = 0; p < 4; ++p){
    int row = p*16 + r16;
    float4 v = *(const float4*)(src + (size_t)(rt*64 + row) * C + ct*64 + c4*4);
    tile[row][c4*4+0] = v.x; tile[row][c4*4+1] = v.y;
    tile[row][c4*4+2] = v.z; tile[row][c4*4+3] = v.w;
  }
  __syncthreads();
  int rr = tid >> 3, cc8 = tid & 7;
  #pragma unroll
  for (int p = 0; p < 2; ++p){
    int n = p*32 + rr;
    unsigned short o[8] __attribute__((aligned(16)));
    #pragma unroll
    for (int j = 0; j < 8; ++j) o[j] = f2bf(tile[cc8*8 + j][n]);
    *(uint4*)(dst + (size_t)(ct*64 + n) * R + rt*64 + cc8*8) = *(const uint4*)o;
  }
}

// ---------------- K0b: small scatter convert for qkvT / denseT ----------------
__global__ __launch_bounds__(256) void prep_small(
    const float* __restrict__ wq_w, const float* __restrict__ wk_w, const float* __restrict__ wv_w,
    const float* __restrict__ dense_w,
    unsigned short* __restrict__ qkvT, unsigned short* __restrict__ denseT){
  int i = blockIdx.x * 256 + threadIdx.x;
  if (i < 98304){
    int k = i & 511; int t = i >> 9; int n = t & 31; int u = t >> 5;
    int p = u % 3, l = u / 3;
    const float* src = (p == 0) ? wq_w : (p == 1) ? wk_w : wv_w;
    qkvT[((size_t)((l*3+p)*S_ + n)) * H_ + k] = f2bf(src[((size_t)(l*H_ + k)) * DK_ + n]);
    return;
  }
  i -= 98304;
  int k = i & 31; int t = i >> 5; int n = t & 511; int l = t >> 9;
  denseT[((size_t)(l*H_ + n)) * DK_ + k] = f2bf(dense_w[((size_t)(l*DK_ + k)) * H_ + n]);
}

// ---------------- K1: build brics rows ----------------
// 8 pairs per block (2 per wave), XCD-swizzled so a batch's 4 blocks share an XCD.
// All 16 gather loads issued before reduction; idx==0 handled branch-free.
__global__ __launch_bounds__(256) void build_brics(
    const float* __restrict__ f_atom, const float* __restrict__ f_group,
    const float* __restrict__ fg, const int* __restrict__ mapping,
    unsigned short* __restrict__ brics){
  int bx = blockIdx.x;                 // 0..4095
  int xcd = bx & 7, idx4 = bx >> 3;    // idx4: 0..511
  int b = xcd * 128 + (idx4 >> 2);     // all 4 blocks of batch b share bx&7
  int sub = idx4 & 3;
  int wv = threadIdx.x >> 6, t = threadIdx.x & 63;
  int c0 = t * 8;

  #pragma unroll
  for (int pp = 0; pp < 2; ++pp){
    int s = sub * 8 + wv * 2 + pp;
    unsigned short* out = brics + (size_t)(b * 32 + s) * K3H_;
    if (s == 0){
      for (int k = t; k < K3H_; k += 64) out[k] = f2bf(fg[k]);
      continue;
    }
    int g = s - 1;
    const int* mp = mapping + ((size_t)(b * G_ + g)) * W_;
    int4 mi0 = *(const int4*)mp;
    int4 mi1 = *(const int4*)(mp + 4);
    int id[8] = {mi0.x, mi0.y, mi0.z, mi0.w, mi1.x, mi1.y, mi1.z, mi1.w};
    const float* base = f_atom + ((size_t)b * A_) * H_ + c0;
    float4 va[8], vb[8];
    #pragma unroll
    for (int w = 0; w < 8; ++w){
      int r = id[w] > 0 ? id[w] - 1 : 0;     // clamped; selected out below if 0
      const float* rowp = base + (size_t)r * H_;
      va[w] = *(const float4*)rowp;
      vb[w] = *(const float4*)(rowp + 4);
    }
    const float* grow = f_group + ((size_t)(b * G_ + g)) * H_ + c0;
    float4 g0 = *(const float4*)grow;
    float4 g1 = *(const float4*)(grow + 4);

    float sum[8], mx[8];
    #pragma unroll
    for (int j = 0; j < 8; ++j){ sum[j] = 0.f; mx[j] = -3.4e38f; }
    #pragma unroll
    for (int w = 0; w < 8; ++w){
      bool z = (id[w] == 0);
      float v[8] = {va[w].x, va[w].y, va[w].z, va[w].w,
                    vb[w].x, vb[w].y, vb[w].z, vb[w].w};
      #pragma unroll
      for (int j = 0; j < 8; ++j){
        float vj = z ? 0.f : v[j];
        sum[j] += vj;
        mx[j] = fmaxf(mx[j], vj);
      }
    }
    float gv[8] = {g0.x, g0.y, g0.z, g0.w, g1.x, g1.y, g1.z, g1.w};
    unsigned short tmp[8] __attribute__((aligned(16)));
    #pragma unroll
    for (int j = 0; j < 8; ++j) tmp[j] = f2bf(sum[j]);
    *(uint4*)(out + c0) = *(const uint4*)tmp;
    #pragma unroll
    for (int j = 0; j < 8; ++j) tmp[j] = f2bf(mx[j]);
    *(uint4*)(out + 512 + c0) = *(const uint4*)tmp;
    #pragma unroll
    for (int j = 0; j < 8; ++j) tmp[j] = f2bf(gv[j]);
    *(uint4*)(out + 1024 + c0) = *(const uint4*)tmp;
  }
}

// ---------------- K2: f_frag = relu(brics @ lr_w + lr_b) ----------------
__global__ __launch_bounds__(256) void gemm_frag(
    const unsigned short* __restrict__ brics, const unsigned short* __restrict__ wT,
    const float* __restrict__ lr_b, unsigned short* __restrict__ f_frag){
  __shared__ __align__(16) unsigned short As[128*64];
  __shared__ __align__(16) unsigned short Bs[128*64];
  int tid = threadIdx.x;
  int bx = blockIdx.x;
  int xcd = bx & 7, slot = bx >> 3;
  int mtile = xcd + 8 * (slot >> 2);
  int ntile = slot & 3;
  int rowStart = mtile * 128, colStart = ntile * 128;
  int lane = tid & 63, wave = tid >> 6;
  int m16 = lane & 15, quad = lane >> 4;
  int wm = wave >> 1, wn = wave & 1;
  floatx4 acc[4][4];
  #pragma unroll
  for (int i = 0; i < 4; ++i)
    #pragma unroll
    for (int j = 0; j < 4; ++j) acc[i][j] = (floatx4){0.f,0.f,0.f,0.f};

  int srow = tid >> 3;
  int gchunk = (tid & 7) ^ (srow & 7);
  size_t aOff[4], bOff[4];
  #pragma unroll
  for (int p = 0; p < 4; ++p){
    aOff[p] = (size_t)(rowStart + p*32 + srow) * K3H_ + gchunk*8;
    bOff[p] = (size_t)(colStart + p*32 + srow) * K3H_ + gchunk*8;
  }
  int fsw0 = ((0*4 + quad) ^ (m16 & 7)) * 8;
  int fsw1 = ((1*4 + quad) ^ (m16 & 7)) * 8;

  for (int kt = 0; kt < K3H_/64; ++kt){
    int kbase = kt * 64;
    #pragma unroll
    for (int p = 0; p < 4; ++p){
      gl_lds16(brics + aOff[p] + kbase, As + p*2048 + (size_t)tid*8);
      gl_lds16(wT    + bOff[p] + kbase, Bs + p*2048 + (size_t)tid*8);
    }
    __syncthreads();
    #pragma unroll
    for (int ks = 0; ks < 2; ++ks){
      int fsw = ks ? fsw1 : fsw0;
      short8 af[4], bfr[4];
      #pragma unroll
      for (int i = 0; i < 4; ++i){
        af[i]  = *(const short8*)(As + (wm*64 + i*16 + m16)*64 + fsw);
        bfr[i] = *(const short8*)(Bs + (wn*64 + i*16 + m16)*64 + fsw);
      }
      #pragma unroll
      for (int i = 0; i < 4; ++i)
        #pragma unroll
        for (int j = 0; j < 4; ++j)
          acc[i][j] = __builtin_amdgcn_mfma_f32_16x16x32_bf16(af[i], bfr[j], acc[i][j], 0, 0, 0);
    }
    __syncthreads();
  }
  #pragma unroll
  for (int i = 0; i < 4; ++i)
    #pragma unroll
    for (int j = 0; j < 4; ++j){
      int col = colStart + wn*64 + j*16 + m16;
      float bias = lr_b[col];
      #pragma unroll
      for (int r = 0; r < 4; ++r){
        int row = rowStart + wm*64 + i*16 + quad*4 + r;
        float v = acc[i][j][r] + bias;
        v = v > 0.f ? v : 0.f;
        f_frag[(size_t)row * H_ + col] = f2bf(v);
      }
    }
}

// ---------------- K3: per-batch fused 2-layer attention ----------------
__global__ __launch_bounds__(256) void attn_kernel(
    const unsigned short* __restrict__ f_frag,
    const unsigned short* __restrict__ qkvT, const unsigned short* __restrict__ denseT,
    const float* __restrict__ wq_b, const float* __restrict__ wk_b, const float* __restrict__ wv_b,
    const float* __restrict__ dense_b, const float* __restrict__ ln_g, const float* __restrict__ ln_b,
    unsigned short* __restrict__ hsf, float* __restrict__ out_attn){
  const int HP = 544, TP = 40;
  __shared__ __align__(16) unsigned short hs[S_*544];
  __shared__ __align__(16) unsigned short Qs[S_*40];
  __shared__ __align__(16) unsigned short Ks[S_*40];
  __shared__ __align__(16) unsigned short Vt[S_*40];
  __shared__ __align__(16) unsigned short Ps[S_*40];
  __shared__ __align__(16) unsigned short Xs[S_*40];
  __shared__ unsigned long long pmask[S_*8];
  __shared__ unsigned int mz[S_];
  int b = blockIdx.x;
  int tid = threadIdx.x;
  int wave = tid >> 6, lane = tid & 63;
  int m16 = lane & 15, quad = lane >> 4;

  {
    int row = tid >> 3, cc = (tid & 7) * 64;
    const unsigned short* src = f_frag + ((size_t)(b * S_ + row)) * H_ + cc;
    unsigned short* dst = hs + row * HP + cc;
    #pragma unroll
    for (int k = 0; k < 64; k += 8)
      *(uint4*)(dst + k) = *(const uint4*)(src + k);
  }
  if (tid < S_) mz[tid] = 0u;
  __syncthreads();
  {
    int s = tid >> 3, w = tid & 7;
    unsigned long long m = 0ull;
    const unsigned short* hrow = hs + s * HP + w * 64;
    for (int j = 0; j < 64; ++j)
      if (hrow[j] != 0) m |= (1ull << j);
    pmask[s * 8 + w] = m;
  }
  __syncthreads();
  for (int idx = tid; idx < S_*S_; idx += 256){
    int s = idx >> 5, t2 = idx & 31;
    bool inter = false;
    #pragma unroll
    for (int w = 0; w < 8; ++w)
      inter = inter || ((pmask[s*8+w] & pmask[t2*8+w]) != 0ull);
    if (!inter) atomicOr(&mz[s], 1u << t2);
  }
  __syncthreads();

  const float scale = 0.17677669529663687f;
  for (int l = 0; l < L_; ++l){
    {
      int mt = wave >> 1, nt = wave & 1;
      floatx4 aq = {0,0,0,0}, ak = {0,0,0,0}, av = {0,0,0,0};
      const unsigned short* arow = hs + (mt*16 + m16) * HP + quad*8;
      const unsigned short* bq = qkvT + ((size_t)((l*3 + 0)*S_ + nt*16 + m16)) * H_ + quad*8;
      const unsigned short* bk = bq + (size_t)S_ * H_;
      const unsigned short* bv = bk + (size_t)S_ * H_;
      for (int k0 = 0; k0 < H_; k0 += 32){
        short8 a = *(const short8*)(arow + k0);
        aq = __builtin_amdgcn_mfma_f32_16x16x32_bf16(a, *(const short8*)(bq + k0), aq, 0,0,0);
        ak = __builtin_amdgcn_mfma_f32_16x16x32_bf16(a, *(const short8*)(bk + k0), ak, 0,0,0);
        av = __builtin_amdgcn_mfma_f32_16x16x32_bf16(a, *(const short8*)(bv + k0), av, 0,0,0);
      }
      int col = nt*16 + m16;
      float bqs = wq_b[l*DK_ + col], bks = wk_b[l*DK_ + col], bvs = wv_b[l*DK_ + col];
      #pragma unroll
      for (int r = 0; r < 4; ++r){
        int rw = mt*16 + quad*4 + r;
        Qs[rw*TP + col] = f2bf((aq[r] + bqs) * scale);
        Ks[rw*TP + col] = f2bf(ak[r] + bks);
        Vt[col*TP + rw] = f2bf(av[r] + bvs);
      }
    }
    __syncthreads();
    if (wave < 2){
      int mt = wave;
      short8 a  = *(const short8*)(Qs + (mt*16 + m16)*TP + quad*8);
      short8 b0 = *(const short8*)(Ks + m16*TP + quad*8);
      short8 b1 = *(const short8*)(Ks + (16 + m16)*TP + quad*8);
      floatx4 z = {0,0,0,0};
      floatx4 s0 = __builtin_amdgcn_mfma_f32_16x16x32_bf16(a, b0, z, 0,0,0);
      floatx4 s1 = __builtin_amdgcn_mfma_f32_16x16x32_bf16(a, b1, z, 0,0,0);
      #pragma unroll
      for (int r = 0; r < 4; ++r){
        int s = mt*16 + quad*4 + r;
        unsigned int m = mz[s];
        float v0 = ((m >> m16) & 1u) ? -1e9f : s0[r];
        float v1 = ((m >> (16 + m16)) & 1u) ? -1e9f : s1[r];
        float mx = fmaxf(v0, v1);
        #pragma unroll
        for (int d = 1; d < 16; d <<= 1) mx = fmaxf(mx, __shfl_xor(mx, d));
        float e0 = __expf(v0 - mx), e1 = __expf(v1 - mx);
        float sm = e0 + e1;
        #pragma unroll
        for (int d = 1; d < 16; d <<= 1) sm += __shfl_xor(sm, d);
        float inv = 1.f / sm;
        float p0 = e0 * inv, p1 = e1 * inv;
        Ps[s*TP + m16] = f2bf(p0);
        Ps[s*TP + 16 + m16] = f2bf(p1);
        if (l == L_ - 1){
          float* oa = out_attn + ((size_t)b * S_ + s) * S_;
          oa[m16] = p0; oa[16 + m16] = p1;
        }
      }
    }
    __syncthreads();
    {
      int mt = wave >> 1, nt = wave & 1;
      short8 a  = *(const short8*)(Ps + (mt*16 + m16)*TP + quad*8);
      short8 bv = *(const short8*)(Vt + (nt*16 + m16)*TP + quad*8);
      floatx4 z = {0,0,0,0};
      floatx4 x = __builtin_amdgcn_mfma_f32_16x16x32_bf16(a, bv, z, 0,0,0);
      #pragma unroll
      for (int r = 0; r < 4; ++r)
        Xs[(mt*16 + quad*4 + r)*TP + nt*16 + m16] = f2bf(x[r]);
    }
    __syncthreads();
    {
      short8 ax0 = *(const short8*)(Xs + m16*TP + quad*8);
      short8 ax1 = *(const short8*)(Xs + (16 + m16)*TP + quad*8);
      #pragma unroll
      for (int j = 0; j < 8; ++j){
        int col = (wave*8 + j)*16 + m16;
        short8 bw = *(const short8*)(denseT + ((size_t)(l*H_ + col)) * DK_ + quad*8);
        float db = dense_b[l*H_ + col];
        floatx4 z = {0,0,0,0};
        floatx4 d0 = __builtin_amdgcn_mfma_f32_16x16x32_bf16(ax0, bw, z, 0,0,0);
        floatx4 d1 = __builtin_amdgcn_mfma_f32_16x16x32_bf16(ax1, bw, z, 0,0,0);
        #pragma unroll
        for (int r = 0; r < 4; ++r){
          int row0 = quad*4 + r;
          float y0 = d0[r] + db + bf2f(hs[row0*HP + col]);
          hs[row0*HP + col] = f2bf(y0);
          int row1 = 16 + quad*4 + r;
          float y1 = d1[r] + db + bf2f(hs[row1*HP + col]);
          hs[row1*HP + col] = f2bf(y1);
        }
      }
    }
    __syncthreads();
    {
      #pragma unroll
      for (int rr = 0; rr < 8; ++rr){
        int row = wave*8 + rr;
        unsigned short* hrow = hs + row*HP + lane*8;
        short8 hv = *(const short8*)hrow;
        float v[8]; float s1 = 0.f, s2 = 0.f;
        #pragma unroll
        for (int j = 0; j < 8; ++j){ v[j] = bf2f((unsigned short)hv[j]); s1 += v[j]; s2 += v[j]*v[j]; }
        #pragma unroll
        for (int d = 1; d < 64; d <<= 1){ s1 += __shfl_xor(s1, d); s2 += __shfl_xor(s2, d); }
        float mean = s1 * (1.f/512.f);
        float var = s2 * (1.f/512.f) - mean*mean;
        float rs = rsqrtf(var + 1e-6f);
        unsigned short o[8] __attribute__((aligned(16)));
        #pragma unroll
        for (int j = 0; j < 8; ++j){
          int colj = lane*8 + j;
          float nv = (v[j] - mean) * rs * ln_g[l*H_ + colj] + ln_b[l*H_ + colj];
          o[j] = f2bf(nv);
        }
        *(uint4*)hrow = *(const uint4*)o;
      }
    }
    __syncthreads();
  }
  if (tid < 64){
    *(uint4*)(hsf + (size_t)b * H_ + tid*8) = *(const uint4*)(hs + tid*8);
  }
}

// ---------------- K4: f_out = LN(hs0 @ lin_w + lin_b; eps 1e-5) * alpha ----------------
__global__ __launch_bounds__(256) void final_kernel(
    const unsigned short* __restrict__ hsf, const unsigned short* __restrict__ lin_wT,
    const float* __restrict__ lin_b, const float* __restrict__ norm_g, const float* __restrict__ norm_b,
    const float* __restrict__ alpha, float* __restrict__ out_f){
  const int HP = 544;
  __shared__ __align__(16) unsigned short hsb[32*544];
  int blk = blockIdx.x;
  int tid = threadIdx.x;
  int wave = tid >> 6, lane = tid & 63;
  int m16 = lane & 15, quad = lane >> 4;
  {
    int row = tid >> 3, cc = (tid & 7) * 64;
    const unsigned short* src = hsf + ((size_t)(blk*32 + row)) * H_ + cc;
    unsigned short* dst = hsb + row*HP + cc;
    #pragma unroll
    for (int k = 0; k < 64; k += 8)
      *(uint4*)(dst + k) = *(const uint4*)(src + k);
  }
  __syncthreads();
  floatx4 acc[2][8];
  #pragma unroll
  for (int mt = 0; mt < 2; ++mt)
    #pragma unroll
    for (int j = 0; j < 8; ++j) acc[mt][j] = (floatx4){0.f,0.f,0.f,0.f};
  for (int k0 = 0; k0 < H_; k0 += 32){
    short8 a0 = *(const short8*)(hsb + m16*HP + k0 + quad*8);
    short8 a1 = *(const short8*)(hsb + (16 + m16)*HP + k0 + quad*8);
    #pragma unroll
    for (int j = 0; j < 8; ++j){
      int n = (wave*8 + j)*16 + m16;
      short8 bw = *(const short8*)(lin_wT + (size_t)n * H_ + k0 + quad*8);
      acc[0][j] = __builtin_amdgcn_mfma_f32_16x16x32_bf16(a0, bw, acc[0][j], 0,0,0);
      acc[1][j] = __builtin_amdgcn_mfma_f32_16x16x32_bf16(a1, bw, acc[1][j], 0,0,0);
    }
  }
  __syncthreads();
  #pragma unroll
  for (int mt = 0; mt < 2; ++mt)
    #pragma unroll
    for (int j = 0; j < 8; ++j){
      int col = (wave*8 + j)*16 + m16;
      float lb = lin_b[col];
      #pragma unroll
      for (int r = 0; r < 4; ++r){
        int row = mt*16 + quad*4 + r;
        hsb[row*HP + col] = f2bf(acc[mt][j][r] + lb);
      }
    }
  __syncthreads();
  float al = alpha[0];
  #pragma unroll
  for (int rr = 0; rr < 8; ++rr){
    int row = wave*8 + rr;
    const unsigned short* hrow = hsb + row*HP + lane*8;
    short8 hv = *(const short8*)hrow;
    float v[8]; float s1 = 0.f, s2 = 0.f;
    #pragma unroll
    for (int j = 0; j < 8; ++j){ v[j] = bf2f((unsigned short)hv[j]); s1 += v[j]; s2 += v[j]*v[j]; }
    #pragma unroll
    for (int d = 1; d < 64; d <<= 1){ s1 += __shfl_xor(s1, d); s2 += __shfl_xor(s2, d); }
    float mean = s1 * (1.f/512.f);
    float var = s2 * (1.f/512.f) - mean*mean;
    float rs = rsqrtf(var + 1e-5f);
    float o[8];
    #pragma unroll
    for (int j = 0; j < 8; ++j){
      int colj = lane*8 + j;
      o[j] = ((v[j] - mean) * rs * norm_g[colj] + norm_b[colj]) * al;
    }
    float* op = out_f + ((size_t)(blk*32 + row)) * H_ + lane*8;
    float4 f0 = {o[0], o[1], o[2], o[3]};
    float4 f1 = {o[4], o[5], o[6], o[7]};
    *(float4*)op = f0;
    *(float4*)(op + 4) = f1;
  }
}

extern "C" void kernel_launch(void* const* d_in, const int* in_sizes, int n_in,
                              void* d_out, int out_size, void* d_ws, size_t ws_size,
                              hipStream_t stream){
  const float* f_atom  = (const float*)d_in[0];
  const float* f_group = (const float*)d_in[1];
  const float* fg      = (const float*)d_in[2];
  const float* alpha   = (const float*)d_in[3];
  const float* lr_w    = (const float*)d_in[4];
  const float* lr_b    = (const float*)d_in[5];
  const float* wq_w    = (const float*)d_in[6];
  const float* wq_b    = (const float*)d_in[7];
  const float* wk_w    = (const float*)d_in[8];
  const float* wk_b    = (const float*)d_in[9];
  const float* wv_w    = (const float*)d_in[10];
  const float* wv_b    = (const float*)d_in[11];
  const float* dense_w = (const float*)d_in[12];
  const float* dense_b = (const float*)d_in[13];
  const float* ln_g    = (const float*)d_in[14];
  const float* ln_b    = (const float*)d_in[15];
  const float* lin_w   = (const float*)d_in[16];
  const float* lin_b   = (const float*)d_in[17];
  const float* norm_g  = (const float*)d_in[18];
  const float* norm_b  = (const float*)d_in[19];
  const int*   mapping = (const int*)d_in[20];

  unsigned short* brics  = (unsigned short*)d_ws;
  unsigned short* f_frag = brics  + (size_t)32768 * 1536;
  unsigned short* lr_wT  = f_frag + (size_t)32768 * 512;
  unsigned short* qkvT   = lr_wT  + (size_t)512 * 1536;
  unsigned short* denseT = qkvT   + (size_t)2*3*32*512;
  unsigned short* lin_wT = denseT + (size_t)2*512*32;
  unsigned short* hsf    = lin_wT + (size_t)512*512;

  float* out_f    = (float*)d_out;
  float* out_attn = out_f + (size_t)B_ * H_;

  prep_transpose<<<256, 256, 0, stream>>>(lr_w, lin_w, lr_wT, lin_wT);
  prep_small<<<512, 256, 0, stream>>>(wq_w, wk_w, wv_w, dense_w, qkvT, denseT);
  build_brics<<<4096, 256, 0, stream>>>(f_atom, f_group, fg, mapping, brics);
  gemm_frag<<<(32768/128) * (512/128), 256, 0, stream>>>(brics, lr_wT, lr_b, f_frag);
  attn_kernel<<<B_, 256, 0, stream>>>(f_frag, qkvT, denseT, wq_b, wk_b, wv_b,
                                      dense_b, ln_g, ln_b, hsf, out_attn);
  final_kernel<<<B_/32, 256, 0, stream>>>(hsf, lin_wT, lin_b, norm_g, norm_b, alpha, out_f);
}

// Round 4
// 476.873 us; speedup vs baseline: 1.0587x; 1.0587x over previous
//
#include <hip/hip_runtime.h>

#define B_   1024
#define A_   64
#define G_   31
#define W_   8
#define H_   512
#define L_   2
#define S_   32
#define DK_  32
#define K3H_ 1536

typedef short short8 __attribute__((ext_vector_type(8)));
typedef float floatx4 __attribute__((ext_vector_type(4)));

__device__ __forceinline__ float bf2f(unsigned short u){
  union { unsigned int i; float f; } x; x.i = ((unsigned int)u) << 16; return x.f;
}
__device__ __forceinline__ unsigned short f2bf(float f){
  union { float f; unsigned int i; } x; x.f = f;
  unsigned int u = x.i;
  return (unsigned short)((u + 0x7FFFu + ((u >> 16) & 1u)) >> 16);
}
__device__ __forceinline__ unsigned long long pack4bf(float a, float b, float c, float d){
  return (unsigned long long)f2bf(a) | ((unsigned long long)f2bf(b) << 16)
       | ((unsigned long long)f2bf(c) << 32) | ((unsigned long long)f2bf(d) << 48);
}
__device__ __forceinline__ void gl_lds16(const unsigned short* g, unsigned short* l){
  __builtin_amdgcn_global_load_lds((const __attribute__((address_space(1))) unsigned int*)g,
                                   (__attribute__((address_space(3))) unsigned int*)l, 16, 0, 0);
}

// ---------------- K0: all weight prep (transpose/convert), one launch ----------------
// blocks 0..255: 64x64 transpose tiles (lr_w then lin_w); blocks 256..767: qkv/dense scatter
__global__ __launch_bounds__(256) void prep_weights(
    const float* __restrict__ lr_w, const float* __restrict__ lin_w,
    const float* __restrict__ wq_w, const float* __restrict__ wk_w, const float* __restrict__ wv_w,
    const float* __restrict__ dense_w,
    unsigned short* __restrict__ lr_wT, unsigned short* __restrict__ lin_wT,
    unsigned short* __restrict__ qkvT, unsigned short* __restrict__ denseT){
  int bx = blockIdx.x;
  int tid = threadIdx.x;
  if (bx < 256){
    __shared__ float tile[64][65];
    const float* src; unsigned short* dst; int R, C;
    if (bx < 192){ src = lr_w;  dst = lr_wT;  R = 1536; C = 512; }
    else         { bx -= 192; src = lin_w; dst = lin_wT; R = 512;  C = 512; }
    int rt = bx >> 3, ct = bx & 7;
    int r16 = tid >> 4, c4 = tid & 15;
    #pragma unroll
    for (int p = 0; p < 4; ++p){
      int row = p*16 + r16;
      float4 v = *(const float4*)(src + (size_t)(rt*64 + row) * C + ct*64 + c4*4);
      tile[row][c4*4+0] = v.x; tile[row][c4*4+1] = v.y;
      tile[row][c4*4+2] = v.z; tile[row][c4*4+3] = v.w;
    }
    __syncthreads();
    int rr = tid >> 3, cc8 = tid & 7;
    #pragma unroll
    for (int p = 0; p < 2; ++p){
      int n = p*32 + rr;
      unsigned short o[8] __attribute__((aligned(16)));
      #pragma unroll
      for (int j = 0; j < 8; ++j) o[j] = f2bf(tile[cc8*8 + j][n]);
      *(uint4*)(dst + (size_t)(ct*64 + n) * R + rt*64 + cc8*8) = *(const uint4*)o;
    }
    return;
  }
  int i = (bx - 256) * 256 + tid;
  if (i < 98304){
    int k = i & 511; int t = i >> 9; int n = t & 31; int u = t >> 5;
    int p = u % 3, l = u / 3;
    const float* src = (p == 0) ? wq_w : (p == 1) ? wk_w : wv_w;
    qkvT[((size_t)((l*3+p)*S_ + n)) * H_ + k] = f2bf(src[((size_t)(l*H_ + k)) * DK_ + n]);
    return;
  }
  i -= 98304;
  if (i < 32768){
    int k = i & 31; int t = i >> 5; int n = t & 511; int l = t >> 9;
    denseT[((size_t)(l*H_ + n)) * DK_ + k] = f2bf(dense_w[((size_t)(l*DK_ + k)) * H_ + n]);
  }
}

// ---------------- K1: build brics rows ----------------
// One block per batch. Stage 64 atom rows (fp32, 256-col phase) in LDS once,
// gather the 31 groups from LDS -> global issued bytes drop ~585MB -> ~300MB.
__global__ __launch_bounds__(256) void build_brics(
    const float* __restrict__ f_atom, const float* __restrict__ f_group,
    const float* __restrict__ fg, const int* __restrict__ mapping,
    unsigned short* __restrict__ brics){
  __shared__ float atoms[64*256];          // 64 KB, exactly the per-WG limit
  int b = blockIdx.x;
  int tid = threadIdx.x;
  int wave = tid >> 6, lane = tid & 63;
  const float* fa = f_atom + (size_t)b * A_ * H_;
  int c4 = lane * 4;

  #pragma unroll
  for (int phase = 0; phase < 2; ++phase){
    int kb = phase * 256;
    // ---- stage: each thread 16 coalesced float4 loads ----
    #pragma unroll
    for (int j = 0; j < 16; ++j){
      int i = j*1024 + tid*4;              // 0..16383
      int r = i >> 8, c = i & 255;
      *(float4*)&atoms[i] = *(const float4*)(fa + (size_t)r*H_ + kb + c);
    }
    __syncthreads();
    // ---- gather: 32 slots, one per (wave,q); all lanes of a slot share the row ----
    #pragma unroll
    for (int q = 0; q < 8; ++q){
      int s = wave*8 + q;
      unsigned short* out = brics + (size_t)(b*32 + s) * K3H_;
      if (s == 0){
        #pragma unroll
        for (int t3 = 0; t3 < 3; ++t3){
          int col = t3*512 + kb + c4;
          float4 v = *(const float4*)(fg + col);
          *(unsigned long long*)(out + col) = pack4bf(v.x, v.y, v.z, v.w);
        }
      } else {
        int g = s - 1;
        const int* mp = mapping + ((size_t)(b * G_ + g)) * W_;
        int4 m0 = *(const int4*)mp;
        int4 m1 = *(const int4*)(mp + 4);
        int id[8] = {m0.x, m0.y, m0.z, m0.w, m1.x, m1.y, m1.z, m1.w};
        float sum[4] = {0.f, 0.f, 0.f, 0.f};
        float mx[4]  = {-3.4e38f, -3.4e38f, -3.4e38f, -3.4e38f};
        #pragma unroll
        for (int w = 0; w < 8; ++w){
          int r = id[w] > 0 ? id[w] - 1 : 0;
          float4 v = *(const float4*)&atoms[r*256 + c4];
          bool z = (id[w] == 0);
          float vv[4] = {z ? 0.f : v.x, z ? 0.f : v.y, z ? 0.f : v.z, z ? 0.f : v.w};
          #pragma unroll
          for (int j = 0; j < 4; ++j){ sum[j] += vv[j]; mx[j] = fmaxf(mx[j], vv[j]); }
        }
        float4 gv = *(const float4*)(f_group + ((size_t)(b * G_ + g)) * H_ + kb + c4);
        *(unsigned long long*)(out + kb + c4)        = pack4bf(sum[0], sum[1], sum[2], sum[3]);
        *(unsigned long long*)(out + 512 + kb + c4)  = pack4bf(mx[0], mx[1], mx[2], mx[3]);
        *(unsigned long long*)(out + 1024 + kb + c4) = pack4bf(gv.x, gv.y, gv.z, gv.w);
      }
    }
    __syncthreads();   // all gathers done before restage
  }
}

// ---------------- K2: f_frag = relu(brics @ lr_w + lr_b) ----------------
__global__ __launch_bounds__(256) void gemm_frag(
    const unsigned short* __restrict__ brics, const unsigned short* __restrict__ wT,
    const float* __restrict__ lr_b, unsigned short* __restrict__ f_frag){
  __shared__ __align__(16) unsigned short As[128*64];
  __shared__ __align__(16) unsigned short Bs[128*64];
  int tid = threadIdx.x;
  int bx = blockIdx.x;
  int xcd = bx & 7, slot = bx >> 3;
  int mtile = xcd + 8 * (slot >> 2);
  int ntile = slot & 3;
  int rowStart = mtile * 128, colStart = ntile * 128;
  int lane = tid & 63, wave = tid >> 6;
  int m16 = lane & 15, quad = lane >> 4;
  int wm = wave >> 1, wn = wave & 1;
  floatx4 acc[4][4];
  #pragma unroll
  for (int i = 0; i < 4; ++i)
    #pragma unroll
    for (int j = 0; j < 4; ++j) acc[i][j] = (floatx4){0.f,0.f,0.f,0.f};

  int srow = tid >> 3;
  int gchunk = (tid & 7) ^ (srow & 7);
  size_t aOff[4], bOff[4];
  #pragma unroll
  for (int p = 0; p < 4; ++p){
    aOff[p] = (size_t)(rowStart + p*32 + srow) * K3H_ + gchunk*8;
    bOff[p] = (size_t)(colStart + p*32 + srow) * K3H_ + gchunk*8;
  }
  int fsw0 = ((0*4 + quad) ^ (m16 & 7)) * 8;
  int fsw1 = ((1*4 + quad) ^ (m16 & 7)) * 8;

  for (int kt = 0; kt < K3H_/64; ++kt){
    int kbase = kt * 64;
    #pragma unroll
    for (int p = 0; p < 4; ++p){
      gl_lds16(brics + aOff[p] + kbase, As + p*2048 + (size_t)tid*8);
      gl_lds16(wT    + bOff[p] + kbase, Bs + p*2048 + (size_t)tid*8);
    }
    __syncthreads();
    #pragma unroll
    for (int ks = 0; ks < 2; ++ks){
      int fsw = ks ? fsw1 : fsw0;
      short8 af[4], bfr[4];
      #pragma unroll
      for (int i = 0; i < 4; ++i){
        af[i]  = *(const short8*)(As + (wm*64 + i*16 + m16)*64 + fsw);
        bfr[i] = *(const short8*)(Bs + (wn*64 + i*16 + m16)*64 + fsw);
      }
      #pragma unroll
      for (int i = 0; i < 4; ++i)
        #pragma unroll
        for (int j = 0; j < 4; ++j)
          acc[i][j] = __builtin_amdgcn_mfma_f32_16x16x32_bf16(af[i], bfr[j], acc[i][j], 0, 0, 0);
    }
    __syncthreads();
  }
  #pragma unroll
  for (int i = 0; i < 4; ++i)
    #pragma unroll
    for (int j = 0; j < 4; ++j){
      int col = colStart + wn*64 + j*16 + m16;
      float bias = lr_b[col];
      #pragma unroll
      for (int r = 0; r < 4; ++r){
        int row = rowStart + wm*64 + i*16 + quad*4 + r;
        float v = acc[i][j][r] + bias;
        v = v > 0.f ? v : 0.f;
        f_frag[(size_t)row * H_ + col] = f2bf(v);
      }
    }
}

// ---------------- K3: per-batch fused 2-layer attention ----------------
__global__ __launch_bounds__(256) void attn_kernel(
    const unsigned short* __restrict__ f_frag,
    const unsigned short* __restrict__ qkvT, const unsigned short* __restrict__ denseT,
    const float* __restrict__ wq_b, const float* __restrict__ wk_b, const float* __restrict__ wv_b,
    const float* __restrict__ dense_b, const float* __restrict__ ln_g, const float* __restrict__ ln_b,
    unsigned short* __restrict__ hsf, float* __restrict__ out_attn){
  const int HP = 544, TP = 40;
  __shared__ __align__(16) unsigned short hs[S_*544];
  __shared__ __align__(16) unsigned short Qs[S_*40];
  __shared__ __align__(16) unsigned short Ks[S_*40];
  __shared__ __align__(16) unsigned short Vt[S_*40];
  __shared__ __align__(16) unsigned short Ps[S_*40];
  __shared__ __align__(16) unsigned short Xs[S_*40];
  __shared__ unsigned long long pmask[S_*8];
  __shared__ unsigned int mz[S_];
  int b = blockIdx.x;
  int tid = threadIdx.x;
  int wave = tid >> 6, lane = tid & 63;
  int m16 = lane & 15, quad = lane >> 4;

  {
    int row = tid >> 3, cc = (tid & 7) * 64;
    const unsigned short* src = f_frag + ((size_t)(b * S_ + row)) * H_ + cc;
    unsigned short* dst = hs + row * HP + cc;
    #pragma unroll
    for (int k = 0; k < 64; k += 8)
      *(uint4*)(dst + k) = *(const uint4*)(src + k);
  }
  if (tid < S_) mz[tid] = 0u;
  __syncthreads();
  {
    int s = tid >> 3, w = tid & 7;
    unsigned long long m = 0ull;
    const unsigned short* hrow = hs + s * HP + w * 64;
    for (int j = 0; j < 64; ++j)
      if (hrow[j] != 0) m |= (1ull << j);
    pmask[s * 8 + w] = m;
  }
  __syncthreads();
  for (int idx = tid; idx < S_*S_; idx += 256){
    int s = idx >> 5, t2 = idx & 31;
    bool inter = false;
    #pragma unroll
    for (int w = 0; w < 8; ++w)
      inter = inter || ((pmask[s*8+w] & pmask[t2*8+w]) != 0ull);
    if (!inter) atomicOr(&mz[s], 1u << t2);
  }
  __syncthreads();

  const float scale = 0.17677669529663687f;
  for (int l = 0; l < L_; ++l){
    {
      int mt = wave >> 1, nt = wave & 1;
      floatx4 aq = {0,0,0,0}, ak = {0,0,0,0}, av = {0,0,0,0};
      const unsigned short* arow = hs + (mt*16 + m16) * HP + quad*8;
      const unsigned short* bq = qkvT + ((size_t)((l*3 + 0)*S_ + nt*16 + m16)) * H_ + quad*8;
      const unsigned short* bk = bq + (size_t)S_ * H_;
      const unsigned short* bv = bk + (size_t)S_ * H_;
      for (int k0 = 0; k0 < H_; k0 += 32){
        short8 a = *(const short8*)(arow + k0);
        aq = __builtin_amdgcn_mfma_f32_16x16x32_bf16(a, *(const short8*)(bq + k0), aq, 0,0,0);
        ak = __builtin_amdgcn_mfma_f32_16x16x32_bf16(a, *(const short8*)(bk + k0), ak, 0,0,0);
        av = __builtin_amdgcn_mfma_f32_16x16x32_bf16(a, *(const short8*)(bv + k0), av, 0,0,0);
      }
      int col = nt*16 + m16;
      float bqs = wq_b[l*DK_ + col], bks = wk_b[l*DK_ + col], bvs = wv_b[l*DK_ + col];
      #pragma unroll
      for (int r = 0; r < 4; ++r){
        int rw = mt*16 + quad*4 + r;
        Qs[rw*TP + col] = f2bf((aq[r] + bqs) * scale);
        Ks[rw*TP + col] = f2bf(ak[r] + bks);
        Vt[col*TP + rw] = f2bf(av[r] + bvs);
      }
    }
    __syncthreads();
    if (wave < 2){
      int mt = wave;
      short8 a  = *(const short8*)(Qs + (mt*16 + m16)*TP + quad*8);
      short8 b0 = *(const short8*)(Ks + m16*TP + quad*8);
      short8 b1 = *(const short8*)(Ks + (16 + m16)*TP + quad*8);
      floatx4 z = {0,0,0,0};
      floatx4 s0 = __builtin_amdgcn_mfma_f32_16x16x32_bf16(a, b0, z, 0,0,0);
      floatx4 s1 = __builtin_amdgcn_mfma_f32_16x16x32_bf16(a, b1, z, 0,0,0);
      #pragma unroll
      for (int r = 0; r < 4; ++r){
        int s = mt*16 + quad*4 + r;
        unsigned int m = mz[s];
        float v0 = ((m >> m16) & 1u) ? -1e9f : s0[r];
        float v1 = ((m >> (16 + m16)) & 1u) ? -1e9f : s1[r];
        float mx = fmaxf(v0, v1);
        #pragma unroll
        for (int d = 1; d < 16; d <<= 1) mx = fmaxf(mx, __shfl_xor(mx, d));
        float e0 = __expf(v0 - mx), e1 = __expf(v1 - mx);
        float sm = e0 + e1;
        #pragma unroll
        for (int d = 1; d < 16; d <<= 1) sm += __shfl_xor(sm, d);
        float inv = 1.f / sm;
        float p0 = e0 * inv, p1 = e1 * inv;
        Ps[s*TP + m16] = f2bf(p0);
        Ps[s*TP + 16 + m16] = f2bf(p1);
        if (l == L_ - 1){
          float* oa = out_attn + ((size_t)b * S_ + s) * S_;
          oa[m16] = p0; oa[16 + m16] = p1;
        }
      }
    }
    __syncthreads();
    {
      int mt = wave >> 1, nt = wave & 1;
      short8 a  = *(const short8*)(Ps + (mt*16 + m16)*TP + quad*8);
      short8 bv = *(const short8*)(Vt + (nt*16 + m16)*TP + quad*8);
      floatx4 z = {0,0,0,0};
      floatx4 x = __builtin_amdgcn_mfma_f32_16x16x32_bf16(a, bv, z, 0,0,0);
      #pragma unroll
      for (int r = 0; r < 4; ++r)
        Xs[(mt*16 + quad*4 + r)*TP + nt*16 + m16] = f2bf(x[r]);
    }
    __syncthreads();
    {
      short8 ax0 = *(const short8*)(Xs + m16*TP + quad*8);
      short8 ax1 = *(const short8*)(Xs + (16 + m16)*TP + quad*8);
      #pragma unroll
      for (int j = 0; j < 8; ++j){
        int col = (wave*8 + j)*16 + m16;
        short8 bw = *(const short8*)(denseT + ((size_t)(l*H_ + col)) * DK_ + quad*8);
        float db = dense_b[l*H_ + col];
        floatx4 z = {0,0,0,0};
        floatx4 d0 = __builtin_amdgcn_mfma_f32_16x16x32_bf16(ax0, bw, z, 0,0,0);
        floatx4 d1 = __builtin_amdgcn_mfma_f32_16x16x32_bf16(ax1, bw, z, 0,0,0);
        #pragma unroll
        for (int r = 0; r < 4; ++r){
          int row0 = quad*4 + r;
          float y0 = d0[r] + db + bf2f(hs[row0*HP + col]);
          hs[row0*HP + col] = f2bf(y0);
          int row1 = 16 + quad*4 + r;
          float y1 = d1[r] + db + bf2f(hs[row1*HP + col]);
          hs[row1*HP + col] = f2bf(y1);
        }
      }
    }
    __syncthreads();
    {
      #pragma unroll
      for (int rr = 0; rr < 8; ++rr){
        int row = wave*8 + rr;
        unsigned short* hrow = hs + row*HP + lane*8;
        short8 hv = *(const short8*)hrow;
        float v[8]; float s1 = 0.f, s2 = 0.f;
        #pragma unroll
        for (int j = 0; j < 8; ++j){ v[j] = bf2f((unsigned short)hv[j]); s1 += v[j]; s2 += v[j]*v[j]; }
        #pragma unroll
        for (int d = 1; d < 64; d <<= 1){ s1 += __shfl_xor(s1, d); s2 += __shfl_xor(s2, d); }
        float mean = s1 * (1.f/512.f);
        float var = s2 * (1.f/512.f) - mean*mean;
        float rs = rsqrtf(var + 1e-6f);
        unsigned short o[8] __attribute__((aligned(16)));
        #pragma unroll
        for (int j = 0; j < 8; ++j){
          int colj = lane*8 + j;
          float nv = (v[j] - mean) * rs * ln_g[l*H_ + colj] + ln_b[l*H_ + colj];
          o[j] = f2bf(nv);
        }
        *(uint4*)hrow = *(const uint4*)o;
      }
    }
    __syncthreads();
  }
  if (tid < 64){
    *(uint4*)(hsf + (size_t)b * H_ + tid*8) = *(const uint4*)(hs + tid*8);
  }
}

// ---------------- K4: f_out = LN(hs0 @ lin_w + lin_b; eps 1e-5) * alpha ----------------
__global__ __launch_bounds__(256) void final_kernel(
    const unsigned short* __restrict__ hsf, const unsigned short* __restrict__ lin_wT,
    const float* __restrict__ lin_b, const float* __restrict__ norm_g, const float* __restrict__ norm_b,
    const float* __restrict__ alpha, float* __restrict__ out_f){
  const int HP = 544;
  __shared__ __align__(16) unsigned short hsb[32*544];
  int blk = blockIdx.x;
  int tid = threadIdx.x;
  int wave = tid >> 6, lane = tid & 63;
  int m16 = lane & 15, quad = lane >> 4;
  {
    int row = tid >> 3, cc = (tid & 7) * 64;
    const unsigned short* src = hsf + ((size_t)(blk*32 + row)) * H_ + cc;
    unsigned short* dst = hsb + row*HP + cc;
    #pragma unroll
    for (int k = 0; k < 64; k += 8)
      *(uint4*)(dst + k) = *(const uint4*)(src + k);
  }
  __syncthreads();
  floatx4 acc[2][8];
  #pragma unroll
  for (int mt = 0; mt < 2; ++mt)
    #pragma unroll
    for (int j = 0; j < 8; ++j) acc[mt][j] = (floatx4){0.f,0.f,0.f,0.f};
  for (int k0 = 0; k0 < H_; k0 += 32){
    short8 a0 = *(const short8*)(hsb + m16*HP + k0 + quad*8);
    short8 a1 = *(const short8*)(hsb + (16 + m16)*HP + k0 + quad*8);
    #pragma unroll
    for (int j = 0; j < 8; ++j){
      int n = (wave*8 + j)*16 + m16;
      short8 bw = *(const short8*)(lin_wT + (size_t)n * H_ + k0 + quad*8);
      acc[0][j] = __builtin_amdgcn_mfma_f32_16x16x32_bf16(a0, bw, acc[0][j], 0,0,0);
      acc[1][j] = __builtin_amdgcn_mfma_f32_16x16x32_bf16(a1, bw, acc[1][j], 0,0,0);
    }
  }
  __syncthreads();
  #pragma unroll
  for (int mt = 0; mt < 2; ++mt)
    #pragma unroll
    for (int j = 0; j < 8; ++j){
      int col = (wave*8 + j)*16 + m16;
      float lb = lin_b[col];
      #pragma unroll
      for (int r = 0; r < 4; ++r){
        int row = mt*16 + quad*4 + r;
        hsb[row*HP + col] = f2bf(acc[mt][j][r] + lb);
      }
    }
  __syncthreads();
  float al = alpha[0];
  #pragma unroll
  for (int rr = 0; rr < 8; ++rr){
    int row = wave*8 + rr;
    const unsigned short* hrow = hsb + row*HP + lane*8;
    short8 hv = *(const short8*)hrow;
    float v[8]; float s1 = 0.f, s2 = 0.f;
    #pragma unroll
    for (int j = 0; j < 8; ++j){ v[j] = bf2f((unsigned short)hv[j]); s1 += v[j]; s2 += v[j]*v[j]; }
    #pragma unroll
    for (int d = 1; d < 64; d <<= 1){ s1 += __shfl_xor(s1, d); s2 += __shfl_xor(s2, d); }
    float mean = s1 * (1.f/512.f);
    float var = s2 * (1.f/512.f) - mean*mean;
    float rs = rsqrtf(var + 1e-5f);
    float o[8];
    #pragma unroll
    for (int j = 0; j < 8; ++j){
      int colj = lane*8 + j;
      o[j] = ((v[j] - mean) * rs * norm_g[colj] + norm_b[colj]) * al;
    }
    float* op = out_f + ((size_t)(blk*32 + row)) * H_ + lane*8;
    float4 f0 = {o[0], o[1], o[2], o[3]};
    float4 f1 = {o[4], o[5], o[6], o[7]};
    *(float4*)op = f0;
    *(float4*)(op + 4) = f1;
  }
}

extern "C" void kernel_launch(void* const* d_in, const int* in_sizes, int n_in,
                              void* d_out, int out_size, void* d_ws, size_t ws_size,
                              hipStream_t stream){
  const float* f_atom  = (const float*)d_in[0];
  const float* f_group = (const float*)d_in[1];
  const float* fg      = (const float*)d_in[2];
  const float* alpha   = (const float*)d_in[3];
  const float* lr_w    = (const float*)d_in[4];
  const float* lr_b    = (const float*)d_in[5];
  const float* wq_w    = (const float*)d_in[6];
  const float* wq_b    = (const float*)d_in[7];
  const float* wk_w    = (const float*)d_in[8];
  const float* wk_b    = (const float*)d_in[9];
  const float* wv_w    = (const float*)d_in[10];
  const float* wv_b    = (const float*)d_in[11];
  const float* dense_w = (const float*)d_in[12];
  const float* dense_b = (const float*)d_in[13];
  const float* ln_g    = (const float*)d_in[14];
  const float* ln_b    = (const float*)d_in[15];
  const float* lin_w   = (const float*)d_in[16];
  const float* lin_b   = (const float*)d_in[17];
  const float* norm_g  = (const float*)d_in[18];
  const float* norm_b  = (const float*)d_in[19];
  const int*   mapping = (const int*)d_in[20];

  unsigned short* brics  = (unsigned short*)d_ws;
  unsigned short* f_frag = brics  + (size_t)32768 * 1536;
  unsigned short* lr_wT  = f_frag + (size_t)32768 * 512;
  unsigned short* qkvT   = lr_wT  + (size_t)512 * 1536;
  unsigned short* denseT = qkvT   + (size_t)2*3*32*512;
  unsigned short* lin_wT = denseT + (size_t)2*512*32;
  unsigned short* hsf    = lin_wT + (size_t)512*512;

  float* out_f    = (float*)d_out;
  float* out_attn = out_f + (size_t)B_ * H_;

  prep_weights<<<768, 256, 0, stream>>>(lr_w, lin_w, wq_w, wk_w, wv_w, dense_w,
                                        lr_wT, lin_wT, qkvT, denseT);
  build_brics<<<B_, 256, 0, stream>>>(f_atom, f_group, fg, mapping, brics);
  gemm_frag<<<(32768/128) * (512/128), 256, 0, stream>>>(brics, lr_wT, lr_b, f_frag);
  attn_kernel<<<B_, 256, 0, stream>>>(f_frag, qkvT, denseT, wq_b, wk_b, wv_b,
                                      dense_b, ln_g, ln_b, hsf, out_attn);
  final_kernel<<<B_/32, 256, 0, stream>>>(hsf, lin_wT, lin_b, norm_g, norm_b, alpha, out_f);
}

// Round 5
// 475.620 us; speedup vs baseline: 1.0615x; 1.0026x over previous
//
#include <hip/hip_runtime.h>

#define B_   1024
#define A_   64
#define G_   31
#define W_   8
#define H_   512
#define L_   2
#define S_   32
#define DK_  32
#define K3H_ 1536

typedef short short8 __attribute__((ext_vector_type(8)));
typedef float floatx4 __attribute__((ext_vector_type(4)));

__device__ __forceinline__ float bf2f(unsigned short u){
  union { unsigned int i; float f; } x; x.i = ((unsigned int)u) << 16; return x.f;
}
__device__ __forceinline__ unsigned short f2bf(float f){
  union { float f; unsigned int i; } x; x.f = f;
  unsigned int u = x.i;
  return (unsigned short)((u + 0x7FFFu + ((u >> 16) & 1u)) >> 16);
}
__device__ __forceinline__ unsigned int pack2bf(float a, float b){
  return (unsigned int)f2bf(a) | ((unsigned int)f2bf(b) << 16);
}
__device__ __forceinline__ void gl_lds16(const unsigned short* g, unsigned short* l){
  __builtin_amdgcn_global_load_lds((const __attribute__((address_space(1))) unsigned int*)g,
                                   (__attribute__((address_space(3))) unsigned int*)l, 16, 0, 0);
}

// ---------------- K0: all weight prep (transpose/convert), one launch ----------------
__global__ __launch_bounds__(256) void prep_weights(
    const float* __restrict__ lr_w, const float* __restrict__ lin_w,
    const float* __restrict__ wq_w, const float* __restrict__ wk_w, const float* __restrict__ wv_w,
    const float* __restrict__ dense_w,
    unsigned short* __restrict__ lr_wT, unsigned short* __restrict__ lin_wT,
    unsigned short* __restrict__ qkvT, unsigned short* __restrict__ denseT){
  int bx = blockIdx.x;
  int tid = threadIdx.x;
  if (bx < 256){
    __shared__ float tile[64][65];
    const float* src; unsigned short* dst; int R, C;
    if (bx < 192){ src = lr_w;  dst = lr_wT;  R = 1536; C = 512; }
    else         { bx -= 192; src = lin_w; dst = lin_wT; R = 512;  C = 512; }
    int rt = bx >> 3, ct = bx & 7;
    int r16 = tid >> 4, c4 = tid & 15;
    #pragma unroll
    for (int p = 0; p < 4; ++p){
      int row = p*16 + r16;
      float4 v = *(const float4*)(src + (size_t)(rt*64 + row) * C + ct*64 + c4*4);
      tile[row][c4*4+0] = v.x; tile[row][c4*4+1] = v.y;
      tile[row][c4*4+2] = v.z; tile[row][c4*4+3] = v.w;
    }
    __syncthreads();
    int rr = tid >> 3, cc8 = tid & 7;
    #pragma unroll
    for (int p = 0; p < 2; ++p){
      int n = p*32 + rr;
      unsigned short o[8] __attribute__((aligned(16)));
      #pragma unroll
      for (int j = 0; j < 8; ++j) o[j] = f2bf(tile[cc8*8 + j][n]);
      *(uint4*)(dst + (size_t)(ct*64 + n) * R + rt*64 + cc8*8) = *(const uint4*)o;
    }
    return;
  }
  int i = (bx - 256) * 256 + tid;
  if (i < 98304){
    int k = i & 511; int t = i >> 9; int n = t & 31; int u = t >> 5;
    int p = u % 3, l = u / 3;
    const float* src = (p == 0) ? wq_w : (p == 1) ? wk_w : wv_w;
    qkvT[((size_t)((l*3+p)*S_ + n)) * H_ + k] = f2bf(src[((size_t)(l*H_ + k)) * DK_ + n]);
    return;
  }
  i -= 98304;
  if (i < 32768){
    int k = i & 31; int t = i >> 5; int n = t & 511; int l = t >> 9;
    denseT[((size_t)(l*H_ + n)) * DK_ + k] = f2bf(dense_w[((size_t)(l*DK_ + k)) * H_ + n]);
  }
}

// ---------------- K1: build brics rows ----------------
// 4 blocks per batch, each owns 128 columns. 32KB LDS stage (fp32), single
// barrier, then the 31 groups gather from LDS. 5 blocks/CU for latency hiding.
__global__ __launch_bounds__(256) void build_brics(
    const float* __restrict__ f_atom, const float* __restrict__ f_group,
    const float* __restrict__ fg, const int* __restrict__ mapping,
    unsigned short* __restrict__ brics){
  __shared__ float atoms[64*128];          // 32 KB
  int bx = blockIdx.x;
  int b = bx >> 2, qc = bx & 3;            // batch, column-quarter
  int kb = qc * 128;
  int tid = threadIdx.x;
  int wave = tid >> 6, lane = tid & 63;
  const float* fa = f_atom + (size_t)b * A_ * H_ + kb;

  // ---- stage: 8 float4 per thread, coalesced (32 lanes span one 512B row) ----
  #pragma unroll
  for (int j = 0; j < 8; ++j){
    int f = j*256 + tid;                   // float4 index 0..2047
    int r = f >> 5, c4v = f & 31;
    *(float4*)&atoms[r*128 + c4v*4] = *(const float4*)(fa + (size_t)r*H_ + c4v*4);
  }
  __syncthreads();

  // ---- gather: 32 slots, one per (wave,q); lane owns 2 columns ----
  int c2 = lane * 2;
  #pragma unroll
  for (int q = 0; q < 8; ++q){
    int s = wave*8 + q;
    unsigned short* out = brics + (size_t)(b*32 + s) * K3H_ + kb;
    if (s == 0){
      #pragma unroll
      for (int t3 = 0; t3 < 3; ++t3){
        const float* fgp = fg + t3*512 + kb + c2;
        *(unsigned int*)(out + t3*512 + c2) = pack2bf(fgp[0], fgp[1]);
      }
    } else {
      int g = s - 1;
      const int* mp = mapping + ((size_t)(b * G_ + g)) * W_;
      int4 m0 = *(const int4*)mp;
      int4 m1 = *(const int4*)(mp + 4);
      int id[8] = {m0.x, m0.y, m0.z, m0.w, m1.x, m1.y, m1.z, m1.w};
      float sum0 = 0.f, sum1 = 0.f;
      float mx0 = -3.4e38f, mx1 = -3.4e38f;
      #pragma unroll
      for (int w = 0; w < 8; ++w){
        int r = id[w] > 0 ? id[w] - 1 : 0;
        float2 v = *(const float2*)&atoms[r*128 + c2];
        bool z = (id[w] == 0);
        float v0 = z ? 0.f : v.x, v1 = z ? 0.f : v.y;
        sum0 += v0; sum1 += v1;
        mx0 = fmaxf(mx0, v0); mx1 = fmaxf(mx1, v1);
      }
      const float* gp = f_group + ((size_t)(b * G_ + g)) * H_ + kb + c2;
      float2 gv = *(const float2*)gp;
      *(unsigned int*)(out + c2)        = pack2bf(sum0, sum1);
      *(unsigned int*)(out + 512 + c2)  = pack2bf(mx0, mx1);
      *(unsigned int*)(out + 1024 + c2) = pack2bf(gv.x, gv.y);
    }
  }
}

// ---------------- K2: f_frag = relu(brics @ lr_w + lr_b) ----------------
__global__ __launch_bounds__(256) void gemm_frag(
    const unsigned short* __restrict__ brics, const unsigned short* __restrict__ wT,
    const float* __restrict__ lr_b, unsigned short* __restrict__ f_frag){
  __shared__ __align__(16) unsigned short As[128*64];
  __shared__ __align__(16) unsigned short Bs[128*64];
  int tid = threadIdx.x;
  int bx = blockIdx.x;
  int xcd = bx & 7, slot = bx >> 3;
  int mtile = xcd + 8 * (slot >> 2);
  int ntile = slot & 3;
  int rowStart = mtile * 128, colStart = ntile * 128;
  int lane = tid & 63, wave = tid >> 6;
  int m16 = lane & 15, quad = lane >> 4;
  int wm = wave >> 1, wn = wave & 1;
  floatx4 acc[4][4];
  #pragma unroll
  for (int i = 0; i < 4; ++i)
    #pragma unroll
    for (int j = 0; j < 4; ++j) acc[i][j] = (floatx4){0.f,0.f,0.f,0.f};

  int srow = tid >> 3;
  int gchunk = (tid & 7) ^ (srow & 7);
  size_t aOff[4], bOff[4];
  #pragma unroll
  for (int p = 0; p < 4; ++p){
    aOff[p] = (size_t)(rowStart + p*32 + srow) * K3H_ + gchunk*8;
    bOff[p] = (size_t)(colStart + p*32 + srow) * K3H_ + gchunk*8;
  }
  int fsw0 = ((0*4 + quad) ^ (m16 & 7)) * 8;
  int fsw1 = ((1*4 + quad) ^ (m16 & 7)) * 8;

  for (int kt = 0; kt < K3H_/64; ++kt){
    int kbase = kt * 64;
    #pragma unroll
    for (int p = 0; p < 4; ++p){
      gl_lds16(brics + aOff[p] + kbase, As + p*2048 + (size_t)tid*8);
      gl_lds16(wT    + bOff[p] + kbase, Bs + p*2048 + (size_t)tid*8);
    }
    __syncthreads();
    #pragma unroll
    for (int ks = 0; ks < 2; ++ks){
      int fsw = ks ? fsw1 : fsw0;
      short8 af[4], bfr[4];
      #pragma unroll
      for (int i = 0; i < 4; ++i){
        af[i]  = *(const short8*)(As + (wm*64 + i*16 + m16)*64 + fsw);
        bfr[i] = *(const short8*)(Bs + (wn*64 + i*16 + m16)*64 + fsw);
      }
      #pragma unroll
      for (int i = 0; i < 4; ++i)
        #pragma unroll
        for (int j = 0; j < 4; ++j)
          acc[i][j] = __builtin_amdgcn_mfma_f32_16x16x32_bf16(af[i], bfr[j], acc[i][j], 0, 0, 0);
    }
    __syncthreads();
  }
  #pragma unroll
  for (int i = 0; i < 4; ++i)
    #pragma unroll
    for (int j = 0; j < 4; ++j){
      int col = colStart + wn*64 + j*16 + m16;
      float bias = lr_b[col];
      #pragma unroll
      for (int r = 0; r < 4; ++r){
        int row = rowStart + wm*64 + i*16 + quad*4 + r;
        float v = acc[i][j][r] + bias;
        v = v > 0.f ? v : 0.f;
        f_frag[(size_t)row * H_ + col] = f2bf(v);
      }
    }
}

// ---------------- K3: per-batch fused 2-layer attention ----------------
__global__ __launch_bounds__(256) void attn_kernel(
    const unsigned short* __restrict__ f_frag,
    const unsigned short* __restrict__ qkvT, const unsigned short* __restrict__ denseT,
    const float* __restrict__ wq_b, const float* __restrict__ wk_b, const float* __restrict__ wv_b,
    const float* __restrict__ dense_b, const float* __restrict__ ln_g, const float* __restrict__ ln_b,
    unsigned short* __restrict__ hsf, float* __restrict__ out_attn){
  const int HP = 544, TP = 40;
  __shared__ __align__(16) unsigned short hs[S_*544];
  __shared__ __align__(16) unsigned short Qs[S_*40];
  __shared__ __align__(16) unsigned short Ks[S_*40];
  __shared__ __align__(16) unsigned short Vt[S_*40];
  __shared__ __align__(16) unsigned short Ps[S_*40];
  __shared__ __align__(16) unsigned short Xs[S_*40];
  __shared__ unsigned long long pmask[S_*8];
  __shared__ unsigned int mz[S_];
  int b = blockIdx.x;
  int tid = threadIdx.x;
  int wave = tid >> 6, lane = tid & 63;
  int m16 = lane & 15, quad = lane >> 4;

  {
    int row = tid >> 3, cc = (tid & 7) * 64;
    const unsigned short* src = f_frag + ((size_t)(b * S_ + row)) * H_ + cc;
    unsigned short* dst = hs + row * HP + cc;
    #pragma unroll
    for (int k = 0; k < 64; k += 8)
      *(uint4*)(dst + k) = *(const uint4*)(src + k);
  }
  if (tid < S_) mz[tid] = 0u;
  __syncthreads();
  {
    int s = tid >> 3, w = tid & 7;
    unsigned long long m = 0ull;
    const unsigned short* hrow = hs + s * HP + w * 64;
    for (int j = 0; j < 64; ++j)
      if (hrow[j] != 0) m |= (1ull << j);
    pmask[s * 8 + w] = m;
  }
  __syncthreads();
  for (int idx = tid; idx < S_*S_; idx += 256){
    int s = idx >> 5, t2 = idx & 31;
    bool inter = false;
    #pragma unroll
    for (int w = 0; w < 8; ++w)
      inter = inter || ((pmask[s*8+w] & pmask[t2*8+w]) != 0ull);
    if (!inter) atomicOr(&mz[s], 1u << t2);
  }
  __syncthreads();

  const float scale = 0.17677669529663687f;
  for (int l = 0; l < L_; ++l){
    {
      int mt = wave >> 1, nt = wave & 1;
      floatx4 aq = {0,0,0,0}, ak = {0,0,0,0}, av = {0,0,0,0};
      const unsigned short* arow = hs + (mt*16 + m16) * HP + quad*8;
      const unsigned short* bq = qkvT + ((size_t)((l*3 + 0)*S_ + nt*16 + m16)) * H_ + quad*8;
      const unsigned short* bk = bq + (size_t)S_ * H_;
      const unsigned short* bv = bk + (size_t)S_ * H_;
      for (int k0 = 0; k0 < H_; k0 += 32){
        short8 a = *(const short8*)(arow + k0);
        aq = __builtin_amdgcn_mfma_f32_16x16x32_bf16(a, *(const short8*)(bq + k0), aq, 0,0,0);
        ak = __builtin_amdgcn_mfma_f32_16x16x32_bf16(a, *(const short8*)(bk + k0), ak, 0,0,0);
        av = __builtin_amdgcn_mfma_f32_16x16x32_bf16(a, *(const short8*)(bv + k0), av, 0,0,0);
      }
      int col = nt*16 + m16;
      float bqs = wq_b[l*DK_ + col], bks = wk_b[l*DK_ + col], bvs = wv_b[l*DK_ + col];
      #pragma unroll
      for (int r = 0; r < 4; ++r){
        int rw = mt*16 + quad*4 + r;
        Qs[rw*TP + col] = f2bf((aq[r] + bqs) * scale);
        Ks[rw*TP + col] = f2bf(ak[r] + bks);
        Vt[col*TP + rw] = f2bf(av[r] + bvs);
      }
    }
    __syncthreads();
    if (wave < 2){
      int mt = wave;
      short8 a  = *(const short8*)(Qs + (mt*16 + m16)*TP + quad*8);
      short8 b0 = *(const short8*)(Ks + m16*TP + quad*8);
      short8 b1 = *(const short8*)(Ks + (16 + m16)*TP + quad*8);
      floatx4 z = {0,0,0,0};
      floatx4 s0 = __builtin_amdgcn_mfma_f32_16x16x32_bf16(a, b0, z, 0,0,0);
      floatx4 s1 = __builtin_amdgcn_mfma_f32_16x16x32_bf16(a, b1, z, 0,0,0);
      #pragma unroll
      for (int r = 0; r < 4; ++r){
        int s = mt*16 + quad*4 + r;
        unsigned int m = mz[s];
        float v0 = ((m >> m16) & 1u) ? -1e9f : s0[r];
        float v1 = ((m >> (16 + m16)) & 1u) ? -1e9f : s1[r];
        float mx = fmaxf(v0, v1);
        #pragma unroll
        for (int d = 1; d < 16; d <<= 1) mx = fmaxf(mx, __shfl_xor(mx, d));
        float e0 = __expf(v0 - mx), e1 = __expf(v1 - mx);
        float sm = e0 + e1;
        #pragma unroll
        for (int d = 1; d < 16; d <<= 1) sm += __shfl_xor(sm, d);
        float inv = 1.f / sm;
        float p0 = e0 * inv, p1 = e1 * inv;
        Ps[s*TP + m16] = f2bf(p0);
        Ps[s*TP + 16 + m16] = f2bf(p1);
        if (l == L_ - 1){
          float* oa = out_attn + ((size_t)b * S_ + s) * S_;
          oa[m16] = p0; oa[16 + m16] = p1;
        }
      }
    }
    __syncthreads();
    {
      int mt = wave >> 1, nt = wave & 1;
      short8 a  = *(const short8*)(Ps + (mt*16 + m16)*TP + quad*8);
      short8 bv = *(const short8*)(Vt + (nt*16 + m16)*TP + quad*8);
      floatx4 z = {0,0,0,0};
      floatx4 x = __builtin_amdgcn_mfma_f32_16x16x32_bf16(a, bv, z, 0,0,0);
      #pragma unroll
      for (int r = 0; r < 4; ++r)
        Xs[(mt*16 + quad*4 + r)*TP + nt*16 + m16] = f2bf(x[r]);
    }
    __syncthreads();
    {
      short8 ax0 = *(const short8*)(Xs + m16*TP + quad*8);
      short8 ax1 = *(const short8*)(Xs + (16 + m16)*TP + quad*8);
      #pragma unroll
      for (int j = 0; j < 8; ++j){
        int col = (wave*8 + j)*16 + m16;
        short8 bw = *(const short8*)(denseT + ((size_t)(l*H_ + col)) * DK_ + quad*8);
        float db = dense_b[l*H_ + col];
        floatx4 z = {0,0,0,0};
        floatx4 d0 = __builtin_amdgcn_mfma_f32_16x16x32_bf16(ax0, bw, z, 0,0,0);
        floatx4 d1 = __builtin_amdgcn_mfma_f32_16x16x32_bf16(ax1, bw, z, 0,0,0);
        #pragma unroll
        for (int r = 0; r < 4; ++r){
          int row0 = quad*4 + r;
          float y0 = d0[r] + db + bf2f(hs[row0*HP + col]);
          hs[row0*HP + col] = f2bf(y0);
          int row1 = 16 + quad*4 + r;
          float y1 = d1[r] + db + bf2f(hs[row1*HP + col]);
          hs[row1*HP + col] = f2bf(y1);
        }
      }
    }
    __syncthreads();
    {
      #pragma unroll
      for (int rr = 0; rr < 8; ++rr){
        int row = wave*8 + rr;
        unsigned short* hrow = hs + row*HP + lane*8;
        short8 hv = *(const short8*)hrow;
        float v[8]; float s1 = 0.f, s2 = 0.f;
        #pragma unroll
        for (int j = 0; j < 8; ++j){ v[j] = bf2f((unsigned short)hv[j]); s1 += v[j]; s2 += v[j]*v[j]; }
        #pragma unroll
        for (int d = 1; d < 64; d <<= 1){ s1 += __shfl_xor(s1, d); s2 += __shfl_xor(s2, d); }
        float mean = s1 * (1.f/512.f);
        float var = s2 * (1.f/512.f) - mean*mean;
        float rs = rsqrtf(var + 1e-6f);
        unsigned short o[8] __attribute__((aligned(16)));
        #pragma unroll
        for (int j = 0; j < 8; ++j){
          int colj = lane*8 + j;
          float nv = (v[j] - mean) * rs * ln_g[l*H_ + colj] + ln_b[l*H_ + colj];
          o[j] = f2bf(nv);
        }
        *(uint4*)hrow = *(const uint4*)o;
      }
    }
    __syncthreads();
  }
  if (tid < 64){
    *(uint4*)(hsf + (size_t)b * H_ + tid*8) = *(const uint4*)(hs + tid*8);
  }
}

// ---------------- K4: f_out = LN(hs0 @ lin_w + lin_b; eps 1e-5) * alpha ----------------
__global__ __launch_bounds__(256) void final_kernel(
    const unsigned short* __restrict__ hsf, const unsigned short* __restrict__ lin_wT,
    const float* __restrict__ lin_b, const float* __restrict__ norm_g, const float* __restrict__ norm_b,
    const float* __restrict__ alpha, float* __restrict__ out_f){
  const int HP = 544;
  __shared__ __align__(16) unsigned short hsb[32*544];
  int blk = blockIdx.x;
  int tid = threadIdx.x;
  int wave = tid >> 6, lane = tid & 63;
  int m16 = lane & 15, quad = lane >> 4;
  {
    int row = tid >> 3, cc = (tid & 7) * 64;
    const unsigned short* src = hsf + ((size_t)(blk*32 + row)) * H_ + cc;
    unsigned short* dst = hsb + row*HP + cc;
    #pragma unroll
    for (int k = 0; k < 64; k += 8)
      *(uint4*)(dst + k) = *(const uint4*)(src + k);
  }
  __syncthreads();
  floatx4 acc[2][8];
  #pragma unroll
  for (int mt = 0; mt < 2; ++mt)
    #pragma unroll
    for (int j = 0; j < 8; ++j) acc[mt][j] = (floatx4){0.f,0.f,0.f,0.f};
  for (int k0 = 0; k0 < H_; k0 += 32){
    short8 a0 = *(const short8*)(hsb + m16*HP + k0 + quad*8);
    short8 a1 = *(const short8*)(hsb + (16 + m16)*HP + k0 + quad*8);
    #pragma unroll
    for (int j = 0; j < 8; ++j){
      int n = (wave*8 + j)*16 + m16;
      short8 bw = *(const short8*)(lin_wT + (size_t)n * H_ + k0 + quad*8);
      acc[0][j] = __builtin_amdgcn_mfma_f32_16x16x32_bf16(a0, bw, acc[0][j], 0,0,0);
      acc[1][j] = __builtin_amdgcn_mfma_f32_16x16x32_bf16(a1, bw, acc[1][j], 0,0,0);
    }
  }
  __syncthreads();
  #pragma unroll
  for (int mt = 0; mt < 2; ++mt)
    #pragma unroll
    for (int j = 0; j < 8; ++j){
      int col = (wave*8 + j)*16 + m16;
      float lb = lin_b[col];
      #pragma unroll
      for (int r = 0; r < 4; ++r){
        int row = mt*16 + quad*4 + r;
        hsb[row*HP + col] = f2bf(acc[mt][j][r] + lb);
      }
    }
  __syncthreads();
  float al = alpha[0];
  #pragma unroll
  for (int rr = 0; rr < 8; ++rr){
    int row = wave*8 + rr;
    const unsigned short* hrow = hsb + row*HP + lane*8;
    short8 hv = *(const short8*)hrow;
    float v[8]; float s1 = 0.f, s2 = 0.f;
    #pragma unroll
    for (int j = 0; j < 8; ++j){ v[j] = bf2f((unsigned short)hv[j]); s1 += v[j]; s2 += v[j]*v[j]; }
    #pragma unroll
    for (int d = 1; d < 64; d <<= 1){ s1 += __shfl_xor(s1, d); s2 += __shfl_xor(s2, d); }
    float mean = s1 * (1.f/512.f);
    float var = s2 * (1.f/512.f) - mean*mean;
    float rs = rsqrtf(var + 1e-5f);
    float o[8];
    #pragma unroll
    for (int j = 0; j < 8; ++j){
      int colj = lane*8 + j;
      o[j] = ((v[j] - mean) * rs * norm_g[colj] + norm_b[colj]) * al;
    }
    float* op = out_f + ((size_t)(blk*32 + row)) * H_ + lane*8;
    float4 f0 = {o[0], o[1], o[2], o[3]};
    float4 f1 = {o[4], o[5], o[6], o[7]};
    *(float4*)op = f0;
    *(float4*)(op + 4) = f1;
  }
}

extern "C" void kernel_launch(void* const* d_in, const int* in_sizes, int n_in,
                              void* d_out, int out_size, void* d_ws, size_t ws_size,
                              hipStream_t stream){
  const float* f_atom  = (const float*)d_in[0];
  const float* f_group = (const float*)d_in[1];
  const float* fg      = (const float*)d_in[2];
  const float* alpha   = (const float*)d_in[3];
  const float* lr_w    = (const float*)d_in[4];
  const float* lr_b    = (const float*)d_in[5];
  const float* wq_w    = (const float*)d_in[6];
  const float* wq_b    = (const float*)d_in[7];
  const float* wk_w    = (const float*)d_in[8];
  const float* wk_b    = (const float*)d_in[9];
  const float* wv_w    = (const float*)d_in[10];
  const float* wv_b    = (const float*)d_in[11];
  const float* dense_w = (const float*)d_in[12];
  const float* dense_b = (const float*)d_in[13];
  const float* ln_g    = (const float*)d_in[14];
  const float* ln_b    = (const float*)d_in[15];
  const float* lin_w   = (const float*)d_in[16];
  const float* lin_b   = (const float*)d_in[17];
  const float* norm_g  = (const float*)d_in[18];
  const float* norm_b  = (const float*)d_in[19];
  const int*   mapping = (const int*)d_in[20];

  unsigned short* brics  = (unsigned short*)d_ws;
  unsigned short* f_frag = brics  + (size_t)32768 * 1536;
  unsigned short* lr_wT  = f_frag + (size_t)32768 * 512;
  unsigned short* qkvT   = lr_wT  + (size_t)512 * 1536;
  unsigned short* denseT = qkvT   + (size_t)2*3*32*512;
  unsigned short* lin_wT = denseT + (size_t)2*512*32;
  unsigned short* hsf    = lin_wT + (size_t)512*512;

  float* out_f    = (float*)d_out;
  float* out_attn = out_f + (size_t)B_ * H_;

  prep_weights<<<768, 256, 0, stream>>>(lr_w, lin_w, wq_w, wk_w, wv_w, dense_w,
                                        lr_wT, lin_wT, qkvT, denseT);
  build_brics<<<B_ * 4, 256, 0, stream>>>(f_atom, f_group, fg, mapping, brics);
  gemm_frag<<<(32768/128) * (512/128), 256, 0, stream>>>(brics, lr_wT, lr_b, f_frag);
  attn_kernel<<<B_, 256, 0, stream>>>(f_frag, qkvT, denseT, wq_b, wk_b, wv_b,
                                      dense_b, ln_g, ln_b, hsf, out_attn);
  final_kernel<<<B_/32, 256, 0, stream>>>(hsf, lin_wT, lin_b, norm_g, norm_b, alpha, out_f);
}

// Round 6
// 464.749 us; speedup vs baseline: 1.0863x; 1.0234x over previous
//
#include <hip/hip_runtime.h>

#define B_   1024
#define A_   64
#define G_   31
#define W_   8
#define H_   512
#define L_   2
#define S_   32
#define DK_  32
#define K3H_ 1536

typedef short short8 __attribute__((ext_vector_type(8)));
typedef float floatx4 __attribute__((ext_vector_type(4)));

__device__ __forceinline__ float bf2f(unsigned short u){
  union { unsigned int i; float f; } x; x.i = ((unsigned int)u) << 16; return x.f;
}
__device__ __forceinline__ unsigned short f2bf(float f){
  union { float f; unsigned int i; } x; x.f = f;
  unsigned int u = x.i;
  return (unsigned short)((u + 0x7FFFu + ((u >> 16) & 1u)) >> 16);
}
__device__ __forceinline__ unsigned int pack2bf(float a, float b){
  return (unsigned int)f2bf(a) | ((unsigned int)f2bf(b) << 16);
}
__device__ __forceinline__ void gl_lds16(const unsigned short* g, unsigned short* l){
  __builtin_amdgcn_global_load_lds((const __attribute__((address_space(1))) unsigned int*)g,
                                   (__attribute__((address_space(3))) unsigned int*)l, 16, 0, 0);
}

// ---------------- K0+K1 fused: weight prep AND brics build in one launch ----------------
// blocks [0,4096): build_brics (4 per batch, 128 cols each, 32KB LDS stage)
// blocks [4096,4352): 64x64 transpose tiles (lr_w, lin_w)
// blocks [4352,4864): qkv/dense scatter convert
__global__ __launch_bounds__(256) void prep_and_build(
    const float* __restrict__ f_atom, const float* __restrict__ f_group,
    const float* __restrict__ fg, const int* __restrict__ mapping,
    const float* __restrict__ lr_w, const float* __restrict__ lin_w,
    const float* __restrict__ wq_w, const float* __restrict__ wk_w, const float* __restrict__ wv_w,
    const float* __restrict__ dense_w,
    unsigned short* __restrict__ brics,
    unsigned short* __restrict__ lr_wT, unsigned short* __restrict__ lin_wT,
    unsigned short* __restrict__ qkvT, unsigned short* __restrict__ denseT){
  __shared__ __align__(16) float ldsf[8192];   // 32 KB shared by both paths
  int bx = blockIdx.x;
  int tid = threadIdx.x;

  if (bx < 4096){
    // ---------------- build_brics ----------------
    int b = bx >> 2, qc = bx & 3;
    int kb = qc * 128;
    int wave = tid >> 6, lane = tid & 63;
    const float* fa = f_atom + (size_t)b * A_ * H_ + kb;
    #pragma unroll
    for (int j = 0; j < 8; ++j){
      int f = j*256 + tid;
      int r = f >> 5, c4v = f & 31;
      *(float4*)&ldsf[r*128 + c4v*4] = *(const float4*)(fa + (size_t)r*H_ + c4v*4);
    }
    __syncthreads();
    int c2 = lane * 2;
    #pragma unroll
    for (int q = 0; q < 8; ++q){
      int s = wave*8 + q;
      unsigned short* out = brics + (size_t)(b*32 + s) * K3H_ + kb;
      if (s == 0){
        #pragma unroll
        for (int t3 = 0; t3 < 3; ++t3){
          const float* fgp = fg + t3*512 + kb + c2;
          *(unsigned int*)(out + t3*512 + c2) = pack2bf(fgp[0], fgp[1]);
        }
      } else {
        int g = s - 1;
        const int* mp = mapping + ((size_t)(b * G_ + g)) * W_;
        int4 m0 = *(const int4*)mp;
        int4 m1 = *(const int4*)(mp + 4);
        int id[8] = {m0.x, m0.y, m0.z, m0.w, m1.x, m1.y, m1.z, m1.w};
        float sum0 = 0.f, sum1 = 0.f;
        float mx0 = -3.4e38f, mx1 = -3.4e38f;
        #pragma unroll
        for (int w = 0; w < 8; ++w){
          int r = id[w] > 0 ? id[w] - 1 : 0;
          float2 v = *(const float2*)&ldsf[r*128 + c2];
          bool z = (id[w] == 0);
          float v0 = z ? 0.f : v.x, v1 = z ? 0.f : v.y;
          sum0 += v0; sum1 += v1;
          mx0 = fmaxf(mx0, v0); mx1 = fmaxf(mx1, v1);
        }
        const float* gp = f_group + ((size_t)(b * G_ + g)) * H_ + kb + c2;
        float2 gv = *(const float2*)gp;
        *(unsigned int*)(out + c2)        = pack2bf(sum0, sum1);
        *(unsigned int*)(out + 512 + c2)  = pack2bf(mx0, mx1);
        *(unsigned int*)(out + 1024 + c2) = pack2bf(gv.x, gv.y);
      }
    }
    return;
  }

  if (bx < 4352){
    // ---------------- 64x64 transpose tiles; ldsf used as tile[64][65] ----------------
    int tb = bx - 4096;
    const float* src; unsigned short* dst; int R, C;
    if (tb < 192){ src = lr_w;  dst = lr_wT;  R = 1536; C = 512; }
    else         { tb -= 192; src = lin_w; dst = lin_wT; R = 512;  C = 512; }
    int rt = tb >> 3, ct = tb & 7;
    int r16 = tid >> 4, c4 = tid & 15;
    #pragma unroll
    for (int p = 0; p < 4; ++p){
      int row = p*16 + r16;
      float4 v = *(const float4*)(src + (size_t)(rt*64 + row) * C + ct*64 + c4*4);
      ldsf[row*65 + c4*4+0] = v.x; ldsf[row*65 + c4*4+1] = v.y;
      ldsf[row*65 + c4*4+2] = v.z; ldsf[row*65 + c4*4+3] = v.w;
    }
    __syncthreads();
    int rr = tid >> 3, cc8 = tid & 7;
    #pragma unroll
    for (int p = 0; p < 2; ++p){
      int n = p*32 + rr;
      unsigned short o[8] __attribute__((aligned(16)));
      #pragma unroll
      for (int j = 0; j < 8; ++j) o[j] = f2bf(ldsf[(cc8*8 + j)*65 + n]);
      *(uint4*)(dst + (size_t)(ct*64 + n) * R + rt*64 + cc8*8) = *(const uint4*)o;
    }
    return;
  }

  // ---------------- qkv/dense scatter convert ----------------
  int i = (bx - 4352) * 256 + tid;
  if (i < 98304){
    int k = i & 511; int t = i >> 9; int n = t & 31; int u = t >> 5;
    int p = u % 3, l = u / 3;
    const float* src = (p == 0) ? wq_w : (p == 1) ? wk_w : wv_w;
    qkvT[((size_t)((l*3+p)*S_ + n)) * H_ + k] = f2bf(src[((size_t)(l*H_ + k)) * DK_ + n]);
    return;
  }
  i -= 98304;
  if (i < 32768){
    int k = i & 31; int t = i >> 5; int n = t & 511; int l = t >> 9;
    denseT[((size_t)(l*H_ + n)) * DK_ + k] = f2bf(dense_w[((size_t)(l*DK_ + k)) * H_ + n]);
  }
}

// ---------------- K2: f_frag = relu(brics @ lr_w + lr_b) ----------------
__global__ __launch_bounds__(256) void gemm_frag(
    const unsigned short* __restrict__ brics, const unsigned short* __restrict__ wT,
    const float* __restrict__ lr_b, unsigned short* __restrict__ f_frag){
  __shared__ __align__(16) unsigned short As[128*64];
  __shared__ __align__(16) unsigned short Bs[128*64];
  int tid = threadIdx.x;
  int bx = blockIdx.x;
  int xcd = bx & 7, slot = bx >> 3;
  int mtile = xcd + 8 * (slot >> 2);
  int ntile = slot & 3;
  int rowStart = mtile * 128, colStart = ntile * 128;
  int lane = tid & 63, wave = tid >> 6;
  int m16 = lane & 15, quad = lane >> 4;
  int wm = wave >> 1, wn = wave & 1;
  floatx4 acc[4][4];
  #pragma unroll
  for (int i = 0; i < 4; ++i)
    #pragma unroll
    for (int j = 0; j < 4; ++j) acc[i][j] = (floatx4){0.f,0.f,0.f,0.f};

  int srow = tid >> 3;
  int gchunk = (tid & 7) ^ (srow & 7);
  size_t aOff[4], bOff[4];
  #pragma unroll
  for (int p = 0; p < 4; ++p){
    aOff[p] = (size_t)(rowStart + p*32 + srow) * K3H_ + gchunk*8;
    bOff[p] = (size_t)(colStart + p*32 + srow) * K3H_ + gchunk*8;
  }
  int fsw0 = ((0*4 + quad) ^ (m16 & 7)) * 8;
  int fsw1 = ((1*4 + quad) ^ (m16 & 7)) * 8;

  for (int kt = 0; kt < K3H_/64; ++kt){
    int kbase = kt * 64;
    #pragma unroll
    for (int p = 0; p < 4; ++p){
      gl_lds16(brics + aOff[p] + kbase, As + p*2048 + (size_t)tid*8);
      gl_lds16(wT    + bOff[p] + kbase, Bs + p*2048 + (size_t)tid*8);
    }
    __syncthreads();
    #pragma unroll
    for (int ks = 0; ks < 2; ++ks){
      int fsw = ks ? fsw1 : fsw0;
      short8 af[4], bfr[4];
      #pragma unroll
      for (int i = 0; i < 4; ++i){
        af[i]  = *(const short8*)(As + (wm*64 + i*16 + m16)*64 + fsw);
        bfr[i] = *(const short8*)(Bs + (wn*64 + i*16 + m16)*64 + fsw);
      }
      #pragma unroll
      for (int i = 0; i < 4; ++i)
        #pragma unroll
        for (int j = 0; j < 4; ++j)
          acc[i][j] = __builtin_amdgcn_mfma_f32_16x16x32_bf16(af[i], bfr[j], acc[i][j], 0, 0, 0);
    }
    __syncthreads();
  }
  #pragma unroll
  for (int i = 0; i < 4; ++i)
    #pragma unroll
    for (int j = 0; j < 4; ++j){
      int col = colStart + wn*64 + j*16 + m16;
      float bias = lr_b[col];
      #pragma unroll
      for (int r = 0; r < 4; ++r){
        int row = rowStart + wm*64 + i*16 + quad*4 + r;
        float v = acc[i][j][r] + bias;
        v = v > 0.f ? v : 0.f;
        f_frag[(size_t)row * H_ + col] = f2bf(v);
      }
    }
}

// ---------------- K3: per-batch fused 2-layer attention ----------------
__global__ __launch_bounds__(256) void attn_kernel(
    const unsigned short* __restrict__ f_frag,
    const unsigned short* __restrict__ qkvT, const unsigned short* __restrict__ denseT,
    const float* __restrict__ wq_b, const float* __restrict__ wk_b, const float* __restrict__ wv_b,
    const float* __restrict__ dense_b, const float* __restrict__ ln_g, const float* __restrict__ ln_b,
    unsigned short* __restrict__ hsf, float* __restrict__ out_attn){
  const int HP = 544, TP = 40;
  __shared__ __align__(16) unsigned short hs[S_*544];
  __shared__ __align__(16) unsigned short Qs[S_*40];
  __shared__ __align__(16) unsigned short Ks[S_*40];
  __shared__ __align__(16) unsigned short Vt[S_*40];
  __shared__ __align__(16) unsigned short Ps[S_*40];
  __shared__ __align__(16) unsigned short Xs[S_*40];
  __shared__ unsigned long long pmask[S_*8];
  __shared__ unsigned int mz[S_];
  int b = blockIdx.x;
  int tid = threadIdx.x;
  int wave = tid >> 6, lane = tid & 63;
  int m16 = lane & 15, quad = lane >> 4;

  {
    int row = tid >> 3, cc = (tid & 7) * 64;
    const unsigned short* src = f_frag + ((size_t)(b * S_ + row)) * H_ + cc;
    unsigned short* dst = hs + row * HP + cc;
    #pragma unroll
    for (int k = 0; k < 64; k += 8)
      *(uint4*)(dst + k) = *(const uint4*)(src + k);
  }
  if (tid < S_) mz[tid] = 0u;
  __syncthreads();
  { // presence bitmask, vectorized b128 reads
    int s = tid >> 3, w = tid & 7;
    const unsigned short* hrow = hs + s * HP + w * 64;
    unsigned long long m = 0ull;
    #pragma unroll
    for (int c = 0; c < 64; c += 8){
      short8 hv = *(const short8*)(hrow + c);
      #pragma unroll
      for (int j = 0; j < 8; ++j)
        if ((unsigned short)hv[j] != 0) m |= (1ull << (c + j));
    }
    pmask[s * 8 + w] = m;
  }
  __syncthreads();
  for (int idx = tid; idx < S_*S_; idx += 256){
    int s = idx >> 5, t2 = idx & 31;
    bool inter = false;
    #pragma unroll
    for (int w = 0; w < 8; ++w)
      inter = inter || ((pmask[s*8+w] & pmask[t2*8+w]) != 0ull);
    if (!inter) atomicOr(&mz[s], 1u << t2);
  }
  __syncthreads();

  const float scale = 0.17677669529663687f;
  for (int l = 0; l < L_; ++l){
    { // (a) QKV
      int mt = wave >> 1, nt = wave & 1;
      floatx4 aq = {0,0,0,0}, ak = {0,0,0,0}, av = {0,0,0,0};
      const unsigned short* arow = hs + (mt*16 + m16) * HP + quad*8;
      const unsigned short* bq = qkvT + ((size_t)((l*3 + 0)*S_ + nt*16 + m16)) * H_ + quad*8;
      const unsigned short* bk = bq + (size_t)S_ * H_;
      const unsigned short* bv = bk + (size_t)S_ * H_;
      for (int k0 = 0; k0 < H_; k0 += 32){
        short8 a = *(const short8*)(arow + k0);
        aq = __builtin_amdgcn_mfma_f32_16x16x32_bf16(a, *(const short8*)(bq + k0), aq, 0,0,0);
        ak = __builtin_amdgcn_mfma_f32_16x16x32_bf16(a, *(const short8*)(bk + k0), ak, 0,0,0);
        av = __builtin_amdgcn_mfma_f32_16x16x32_bf16(a, *(const short8*)(bv + k0), av, 0,0,0);
      }
      int col = nt*16 + m16;
      float bqs = wq_b[l*DK_ + col], bks = wk_b[l*DK_ + col], bvs = wv_b[l*DK_ + col];
      #pragma unroll
      for (int r = 0; r < 4; ++r){
        int rw = mt*16 + quad*4 + r;
        Qs[rw*TP + col] = f2bf((aq[r] + bqs) * scale);
        Ks[rw*TP + col] = f2bf(ak[r] + bks);
        Vt[col*TP + rw] = f2bf(av[r] + bvs);
      }
    }
    __syncthreads();
    if (wave < 2){ // (b) scores + mask + softmax
      int mt = wave;
      short8 a  = *(const short8*)(Qs + (mt*16 + m16)*TP + quad*8);
      short8 b0 = *(const short8*)(Ks + m16*TP + quad*8);
      short8 b1 = *(const short8*)(Ks + (16 + m16)*TP + quad*8);
      floatx4 z = {0,0,0,0};
      floatx4 s0 = __builtin_amdgcn_mfma_f32_16x16x32_bf16(a, b0, z, 0,0,0);
      floatx4 s1 = __builtin_amdgcn_mfma_f32_16x16x32_bf16(a, b1, z, 0,0,0);
      #pragma unroll
      for (int r = 0; r < 4; ++r){
        int s = mt*16 + quad*4 + r;
        unsigned int m = mz[s];
        float v0 = ((m >> m16) & 1u) ? -1e9f : s0[r];
        float v1 = ((m >> (16 + m16)) & 1u) ? -1e9f : s1[r];
        float mx = fmaxf(v0, v1);
        #pragma unroll
        for (int d = 1; d < 16; d <<= 1) mx = fmaxf(mx, __shfl_xor(mx, d));
        float e0 = __expf(v0 - mx), e1 = __expf(v1 - mx);
        float sm = e0 + e1;
        #pragma unroll
        for (int d = 1; d < 16; d <<= 1) sm += __shfl_xor(sm, d);
        float inv = 1.f / sm;
        float p0 = e0 * inv, p1 = e1 * inv;
        Ps[s*TP + m16] = f2bf(p0);
        Ps[s*TP + 16 + m16] = f2bf(p1);
        if (l == L_ - 1){
          float* oa = out_attn + ((size_t)b * S_ + s) * S_;
          oa[m16] = p0; oa[16 + m16] = p1;
        }
      }
    }
    __syncthreads();
    { // (c) X = P @ V
      int mt = wave >> 1, nt = wave & 1;
      short8 a  = *(const short8*)(Ps + (mt*16 + m16)*TP + quad*8);
      short8 bv = *(const short8*)(Vt + (nt*16 + m16)*TP + quad*8);
      floatx4 z = {0,0,0,0};
      floatx4 x = __builtin_amdgcn_mfma_f32_16x16x32_bf16(a, bv, z, 0,0,0);
      #pragma unroll
      for (int r = 0; r < 4; ++r)
        Xs[(mt*16 + quad*4 + r)*TP + nt*16 + m16] = f2bf(x[r]);
    }
    __syncthreads();
    { // (d) dh^T = denseT @ X^T: lane owns 4 consecutive dense-cols of row s -> b64 residual RMW
      short8 bx0 = *(const short8*)(Xs + m16*TP + quad*8);          // B[n=s 0..15][k]
      short8 bx1 = *(const short8*)(Xs + (16 + m16)*TP + quad*8);   // B[n=s 16..31][k]
      #pragma unroll
      for (int j = 0; j < 8; ++j){
        int dct = wave*8 + j;                 // dense-col tile 0..31
        short8 aw = *(const short8*)(denseT + ((size_t)(l*H_ + dct*16 + m16)) * DK_ + quad*8);
        floatx4 z = {0,0,0,0};
        floatx4 d0 = __builtin_amdgcn_mfma_f32_16x16x32_bf16(aw, bx0, z, 0,0,0);
        floatx4 d1 = __builtin_amdgcn_mfma_f32_16x16x32_bf16(aw, bx1, z, 0,0,0);
        int dc0 = dct*16 + quad*4;
        float4 db4 = *(const float4*)(dense_b + l*H_ + dc0);
        const float dbr[4] = {db4.x, db4.y, db4.z, db4.w};
        unsigned short* h0 = hs + m16*HP + dc0;
        unsigned short* h1 = hs + (16 + m16)*HP + dc0;
        unsigned long long u0 = *(unsigned long long*)h0;
        unsigned long long u1 = *(unsigned long long*)h1;
        unsigned long long o0 = 0ull, o1 = 0ull;
        #pragma unroll
        for (int r = 0; r < 4; ++r){
          float hv0 = bf2f((unsigned short)(u0 >> (16*r)));
          float hv1 = bf2f((unsigned short)(u1 >> (16*r)));
          o0 |= (unsigned long long)f2bf(d0[r] + dbr[r] + hv0) << (16*r);
          o1 |= (unsigned long long)f2bf(d1[r] + dbr[r] + hv1) << (16*r);
        }
        *(unsigned long long*)h0 = o0;
        *(unsigned long long*)h1 = o1;
      }
    }
    __syncthreads();
    { // (e) layernorm per row (eps 1e-6)
      #pragma unroll
      for (int rr = 0; rr < 8; ++rr){
        int row = wave*8 + rr;
        unsigned short* hrow = hs + row*HP + lane*8;
        short8 hv = *(const short8*)hrow;
        float v[8]; float s1 = 0.f, s2 = 0.f;
        #pragma unroll
        for (int j = 0; j < 8; ++j){ v[j] = bf2f((unsigned short)hv[j]); s1 += v[j]; s2 += v[j]*v[j]; }
        #pragma unroll
        for (int d = 1; d < 64; d <<= 1){ s1 += __shfl_xor(s1, d); s2 += __shfl_xor(s2, d); }
        float mean = s1 * (1.f/512.f);
        float var = s2 * (1.f/512.f) - mean*mean;
        float rs = rsqrtf(var + 1e-6f);
        unsigned short o[8] __attribute__((aligned(16)));
        #pragma unroll
        for (int j = 0; j < 8; ++j){
          int colj = lane*8 + j;
          float nv = (v[j] - mean) * rs * ln_g[l*H_ + colj] + ln_b[l*H_ + colj];
          o[j] = f2bf(nv);
        }
        *(uint4*)hrow = *(const uint4*)o;
      }
    }
    __syncthreads();
  }
  if (tid < 64){
    *(uint4*)(hsf + (size_t)b * H_ + tid*8) = *(const uint4*)(hs + tid*8);
  }
}

// ---------------- K4: f_out = LN(hs0 @ lin_w + lin_b; eps 1e-5) * alpha ----------------
__global__ __launch_bounds__(256) void final_kernel(
    const unsigned short* __restrict__ hsf, const unsigned short* __restrict__ lin_wT,
    const float* __restrict__ lin_b, const float* __restrict__ norm_g, const float* __restrict__ norm_b,
    const float* __restrict__ alpha, float* __restrict__ out_f){
  const int HP = 544;
  __shared__ __align__(16) unsigned short hsb[32*544];
  int blk = blockIdx.x;
  int tid = threadIdx.x;
  int wave = tid >> 6, lane = tid & 63;
  int m16 = lane & 15, quad = lane >> 4;
  {
    int row = tid >> 3, cc = (tid & 7) * 64;
    const unsigned short* src = hsf + ((size_t)(blk*32 + row)) * H_ + cc;
    unsigned short* dst = hsb + row*HP + cc;
    #pragma unroll
    for (int k = 0; k < 64; k += 8)
      *(uint4*)(dst + k) = *(const uint4*)(src + k);
  }
  __syncthreads();
  floatx4 acc[2][8];
  #pragma unroll
  for (int mt = 0; mt < 2; ++mt)
    #pragma unroll
    for (int j = 0; j < 8; ++j) acc[mt][j] = (floatx4){0.f,0.f,0.f,0.f};
  for (int k0 = 0; k0 < H_; k0 += 32){
    short8 a0 = *(const short8*)(hsb + m16*HP + k0 + quad*8);
    short8 a1 = *(const short8*)(hsb + (16 + m16)*HP + k0 + quad*8);
    #pragma unroll
    for (int j = 0; j < 8; ++j){
      int n = (wave*8 + j)*16 + m16;
      short8 bw = *(const short8*)(lin_wT + (size_t)n * H_ + k0 + quad*8);
      acc[0][j] = __builtin_amdgcn_mfma_f32_16x16x32_bf16(a0, bw, acc[0][j], 0,0,0);
      acc[1][j] = __builtin_amdgcn_mfma_f32_16x16x32_bf16(a1, bw, acc[1][j], 0,0,0);
    }
  }
  __syncthreads();
  #pragma unroll
  for (int mt = 0; mt < 2; ++mt)
    #pragma unroll
    for (int j = 0; j < 8; ++j){
      int col = (wave*8 + j)*16 + m16;
      float lb = lin_b[col];
      #pragma unroll
      for (int r = 0; r < 4; ++r){
        int row = mt*16 + quad*4 + r;
        hsb[row*HP + col] = f2bf(acc[mt][j][r] + lb);
      }
    }
  __syncthreads();
  float al = alpha[0];
  #pragma unroll
  for (int rr = 0; rr < 8; ++rr){
    int row = wave*8 + rr;
    const unsigned short* hrow = hsb + row*HP + lane*8;
    short8 hv = *(const short8*)hrow;
    float v[8]; float s1 = 0.f, s2 = 0.f;
    #pragma unroll
    for (int j = 0; j < 8; ++j){ v[j] = bf2f((unsigned short)hv[j]); s1 += v[j]; s2 += v[j]*v[j]; }
    #pragma unroll
    for (int d = 1; d < 64; d <<= 1){ s1 += __shfl_xor(s1, d); s2 += __shfl_xor(s2, d); }
    float mean = s1 * (1.f/512.f);
    float var = s2 * (1.f/512.f) - mean*mean;
    float rs = rsqrtf(var + 1e-5f);
    float o[8];
    #pragma unroll
    for (int j = 0; j < 8; ++j){
      int colj = lane*8 + j;
      o[j] = ((v[j] - mean) * rs * norm_g[colj] + norm_b[colj]) * al;
    }
    float* op = out_f + ((size_t)(blk*32 + row)) * H_ + lane*8;
    float4 f0 = {o[0], o[1], o[2], o[3]};
    float4 f1 = {o[4], o[5], o[6], o[7]};
    *(float4*)op = f0;
    *(float4*)(op + 4) = f1;
  }
}

extern "C" void kernel_launch(void* const* d_in, const int* in_sizes, int n_in,
                              void* d_out, int out_size, void* d_ws, size_t ws_size,
                              hipStream_t stream){
  const float* f_atom  = (const float*)d_in[0];
  const float* f_group = (const float*)d_in[1];
  const float* fg      = (const float*)d_in[2];
  const float* alpha   = (const float*)d_in[3];
  const float* lr_w    = (const float*)d_in[4];
  const float* lr_b    = (const float*)d_in[5];
  const float* wq_w    = (const float*)d_in[6];
  const float* wq_b    = (const float*)d_in[7];
  const float* wk_w    = (const float*)d_in[8];
  const float* wk_b    = (const float*)d_in[9];
  const float* wv_w    = (const float*)d_in[10];
  const float* wv_b    = (const float*)d_in[11];
  const float* dense_w = (const float*)d_in[12];
  const float* dense_b = (const float*)d_in[13];
  const float* ln_g    = (const float*)d_in[14];
  const float* ln_b    = (const float*)d_in[15];
  const float* lin_w   = (const float*)d_in[16];
  const float* lin_b   = (const float*)d_in[17];
  const float* norm_g  = (const float*)d_in[18];
  const float* norm_b  = (const float*)d_in[19];
  const int*   mapping = (const int*)d_in[20];

  unsigned short* brics  = (unsigned short*)d_ws;
  unsigned short* f_frag = brics  + (size_t)32768 * 1536;
  unsigned short* lr_wT  = f_frag + (size_t)32768 * 512;
  unsigned short* qkvT   = lr_wT  + (size_t)512 * 1536;
  unsigned short* denseT = qkvT   + (size_t)2*3*32*512;
  unsigned short* lin_wT = denseT + (size_t)2*512*32;
  unsigned short* hsf    = lin_wT + (size_t)512*512;

  float* out_f    = (float*)d_out;
  float* out_attn = out_f + (size_t)B_ * H_;

  prep_and_build<<<4864, 256, 0, stream>>>(f_atom, f_group, fg, mapping,
                                           lr_w, lin_w, wq_w, wk_w, wv_w, dense_w,
                                           brics, lr_wT, lin_wT, qkvT, denseT);
  gemm_frag<<<(32768/128) * (512/128), 256, 0, stream>>>(brics, lr_wT, lr_b, f_frag);
  attn_kernel<<<B_, 256, 0, stream>>>(f_frag, qkvT, denseT, wq_b, wk_b, wv_b,
                                      dense_b, ln_g, ln_b, hsf, out_attn);
  final_kernel<<<B_/32, 256, 0, stream>>>(hsf, lin_wT, lin_b, norm_g, norm_b, alpha, out_f);
}

// Round 7
// 456.151 us; speedup vs baseline: 1.1068x; 1.0188x over previous
//
#include <hip/hip_runtime.h>

#define B_   1024
#define A_   64
#define G_   31
#define W_   8
#define H_   512
#define L_   2
#define S_   32
#define DK_  32
#define K3H_ 1536

typedef short short8 __attribute__((ext_vector_type(8)));
typedef float floatx4 __attribute__((ext_vector_type(4)));

__device__ __forceinline__ float bf2f(unsigned short u){
  union { unsigned int i; float f; } x; x.i = ((unsigned int)u) << 16; return x.f;
}
__device__ __forceinline__ unsigned short f2bf(float f){
  union { float f; unsigned int i; } x; x.f = f;
  unsigned int u = x.i;
  return (unsigned short)((u + 0x7FFFu + ((u >> 16) & 1u)) >> 16);
}
__device__ __forceinline__ unsigned int pack2bf(float a, float b){
  return (unsigned int)f2bf(a) | ((unsigned int)f2bf(b) << 16);
}
__device__ __forceinline__ void gl_lds16(const unsigned short* g, unsigned short* l){
  __builtin_amdgcn_global_load_lds((const __attribute__((address_space(1))) unsigned int*)g,
                                   (__attribute__((address_space(3))) unsigned int*)l, 16, 0, 0);
}

// ---------------- K0+K1 fused, 512-thread blocks ----------------
// [0,4096):      gather blocks: stage 64x128 f_atom cols in LDS, write sum|max sections
// [4096,8064):   f_group -> brics group-section streaming convert (3968 blocks x 4096 elems)
// [8064,8448):   fg -> brics s=0 rows (384 blocks)
// [8448,8704):   64x64 transpose tiles (lr_w, lin_w) - threads 0..255 active
// [8704,8960):   qkv/dense scatter convert
__global__ __launch_bounds__(512) void prep_and_build(
    const float* __restrict__ f_atom, const float* __restrict__ f_group,
    const float* __restrict__ fg, const int* __restrict__ mapping,
    const float* __restrict__ lr_w, const float* __restrict__ lin_w,
    const float* __restrict__ wq_w, const float* __restrict__ wk_w, const float* __restrict__ wv_w,
    const float* __restrict__ dense_w,
    unsigned short* __restrict__ brics,
    unsigned short* __restrict__ lr_wT, unsigned short* __restrict__ lin_wT,
    unsigned short* __restrict__ qkvT, unsigned short* __restrict__ denseT){
  __shared__ __align__(16) float ldsf[8192];   // 32 KB
  int bx = blockIdx.x;
  int tid = threadIdx.x;

  if (bx < 4096){
    // ---------------- gather: one (batch, 128-col quarter), 8 waves ----------------
    int b = bx >> 2, qc = bx & 3;
    int kb = qc * 128;
    int wave = tid >> 6, lane = tid & 63;
    const float* fa = f_atom + (size_t)b * A_ * H_ + kb;
    #pragma unroll
    for (int j = 0; j < 4; ++j){
      int f = j*512 + tid;                 // float4 index 0..2047
      int r = f >> 5, c4v = f & 31;
      *(float4*)&ldsf[r*128 + c4v*4] = *(const float4*)(fa + (size_t)r*H_ + c4v*4);
    }
    __syncthreads();
    int c2 = lane * 2;
    #pragma unroll
    for (int q = 0; q < 4; ++q){
      int s = wave*4 + q;                  // 0..31; s==0 handled by fg streaming blocks
      if (s == 0) continue;
      int g = s - 1;
      unsigned short* out = brics + (size_t)(b*32 + s) * K3H_ + kb;
      const int* mp = mapping + ((size_t)(b * G_ + g)) * W_;
      int4 m0 = *(const int4*)mp;
      int4 m1 = *(const int4*)(mp + 4);
      int id[8] = {m0.x, m0.y, m0.z, m0.w, m1.x, m1.y, m1.z, m1.w};
      float sum0 = 0.f, sum1 = 0.f;
      float mx0 = -3.4e38f, mx1 = -3.4e38f;
      #pragma unroll
      for (int w = 0; w < 8; ++w){
        int r = id[w] > 0 ? id[w] - 1 : 0;
        float2 v = *(const float2*)&ldsf[r*128 + c2];
        bool z = (id[w] == 0);
        float v0 = z ? 0.f : v.x, v1 = z ? 0.f : v.y;
        sum0 += v0; sum1 += v1;
        mx0 = fmaxf(mx0, v0); mx1 = fmaxf(mx1, v1);
      }
      *(unsigned int*)(out + c2)       = pack2bf(sum0, sum1);
      *(unsigned int*)(out + 512 + c2) = pack2bf(mx0, mx1);
    }
    return;
  }

  if (bx < 8064){
    // ---------------- f_group -> brics[b][g+1][1024..1536] ----------------
    int pair = (bx - 4096) * 8 + (tid >> 6);     // 0..31743 (1024*31)
    int c0 = (tid & 63) * 8;
    int b = pair / G_, g = pair - b * G_;
    const float* src = f_group + (size_t)pair * H_ + c0;
    float4 v0 = *(const float4*)src;
    float4 v1 = *(const float4*)(src + 4);
    unsigned short o[8] __attribute__((aligned(16)));
    o[0]=f2bf(v0.x); o[1]=f2bf(v0.y); o[2]=f2bf(v0.z); o[3]=f2bf(v0.w);
    o[4]=f2bf(v1.x); o[5]=f2bf(v1.y); o[6]=f2bf(v1.z); o[7]=f2bf(v1.w);
    *(uint4*)(brics + (size_t)(b*32 + g + 1) * K3H_ + 1024 + c0) = *(const uint4*)o;
    return;
  }

  if (bx < 8448){
    // ---------------- fg -> brics[b][0][0..1536] ----------------
    int e = (bx - 8064) * 4096 + tid * 8;        // 0..1572863 (1024*1536)
    int batch = e / K3H_, c = e - batch * K3H_;
    const float* src = fg + c;
    float4 v0 = *(const float4*)src;
    float4 v1 = *(const float4*)(src + 4);
    unsigned short o[8] __attribute__((aligned(16)));
    o[0]=f2bf(v0.x); o[1]=f2bf(v0.y); o[2]=f2bf(v0.z); o[3]=f2bf(v0.w);
    o[4]=f2bf(v1.x); o[5]=f2bf(v1.y); o[6]=f2bf(v1.z); o[7]=f2bf(v1.w);
    *(uint4*)(brics + (size_t)batch*32*K3H_ + c) = *(const uint4*)o;
    return;
  }

  if (bx < 8704){
    // ---------------- 64x64 transpose tiles (threads 0..255) ----------------
    int tb = bx - 8448;
    const float* src; unsigned short* dst; int R, C;
    if (tb < 192){ src = lr_w;  dst = lr_wT;  R = 1536; C = 512; }
    else         { tb -= 192; src = lin_w; dst = lin_wT; R = 512;  C = 512; }
    int rt = tb >> 3, ct = tb & 7;
    if (tid < 256){
      int r16 = tid >> 4, c4 = tid & 15;
      #pragma unroll
      for (int p = 0; p < 4; ++p){
        int row = p*16 + r16;
        float4 v = *(const float4*)(src + (size_t)(rt*64 + row) * C + ct*64 + c4*4);
        ldsf[row*65 + c4*4+0] = v.x; ldsf[row*65 + c4*4+1] = v.y;
        ldsf[row*65 + c4*4+2] = v.z; ldsf[row*65 + c4*4+3] = v.w;
      }
    }
    __syncthreads();
    if (tid < 256){
      int rr = tid >> 3, cc8 = tid & 7;
      #pragma unroll
      for (int p = 0; p < 2; ++p){
        int n = p*32 + rr;
        unsigned short o[8] __attribute__((aligned(16)));
        #pragma unroll
        for (int j = 0; j < 8; ++j) o[j] = f2bf(ldsf[(cc8*8 + j)*65 + n]);
        *(uint4*)(dst + (size_t)(ct*64 + n) * R + rt*64 + cc8*8) = *(const uint4*)o;
      }
    }
    return;
  }

  // ---------------- qkv/dense scatter convert ----------------
  int i = (bx - 8704) * 512 + tid;
  if (i < 98304){
    int k = i & 511; int t = i >> 9; int n = t & 31; int u = t >> 5;
    int p = u % 3, l = u / 3;
    const float* src = (p == 0) ? wq_w : (p == 1) ? wk_w : wv_w;
    qkvT[((size_t)((l*3+p)*S_ + n)) * H_ + k] = f2bf(src[((size_t)(l*H_ + k)) * DK_ + n]);
    return;
  }
  i -= 98304;
  if (i < 32768){
    int k = i & 31; int t = i >> 5; int n = t & 511; int l = t >> 9;
    denseT[((size_t)(l*H_ + n)) * DK_ + k] = f2bf(dense_w[((size_t)(l*DK_ + k)) * H_ + n]);
  }
}

// ---------------- K2: f_frag = relu(brics @ lr_w + lr_b) ----------------
__global__ __launch_bounds__(256) void gemm_frag(
    const unsigned short* __restrict__ brics, const unsigned short* __restrict__ wT,
    const float* __restrict__ lr_b, unsigned short* __restrict__ f_frag){
  __shared__ __align__(16) unsigned short As[128*64];
  __shared__ __align__(16) unsigned short Bs[128*64];
  int tid = threadIdx.x;
  int bx = blockIdx.x;
  int xcd = bx & 7, slot = bx >> 3;
  int mtile = xcd + 8 * (slot >> 2);
  int ntile = slot & 3;
  int rowStart = mtile * 128, colStart = ntile * 128;
  int lane = tid & 63, wave = tid >> 6;
  int m16 = lane & 15, quad = lane >> 4;
  int wm = wave >> 1, wn = wave & 1;
  floatx4 acc[4][4];
  #pragma unroll
  for (int i = 0; i < 4; ++i)
    #pragma unroll
    for (int j = 0; j < 4; ++j) acc[i][j] = (floatx4){0.f,0.f,0.f,0.f};

  int srow = tid >> 3;
  int gchunk = (tid & 7) ^ (srow & 7);
  size_t aOff[4], bOff[4];
  #pragma unroll
  for (int p = 0; p < 4; ++p){
    aOff[p] = (size_t)(rowStart + p*32 + srow) * K3H_ + gchunk*8;
    bOff[p] = (size_t)(colStart + p*32 + srow) * K3H_ + gchunk*8;
  }
  int fsw0 = ((0*4 + quad) ^ (m16 & 7)) * 8;
  int fsw1 = ((1*4 + quad) ^ (m16 & 7)) * 8;

  for (int kt = 0; kt < K3H_/64; ++kt){
    int kbase = kt * 64;
    #pragma unroll
    for (int p = 0; p < 4; ++p){
      gl_lds16(brics + aOff[p] + kbase, As + p*2048 + (size_t)tid*8);
      gl_lds16(wT    + bOff[p] + kbase, Bs + p*2048 + (size_t)tid*8);
    }
    __syncthreads();
    #pragma unroll
    for (int ks = 0; ks < 2; ++ks){
      int fsw = ks ? fsw1 : fsw0;
      short8 af[4], bfr[4];
      #pragma unroll
      for (int i = 0; i < 4; ++i){
        af[i]  = *(const short8*)(As + (wm*64 + i*16 + m16)*64 + fsw);
        bfr[i] = *(const short8*)(Bs + (wn*64 + i*16 + m16)*64 + fsw);
      }
      #pragma unroll
      for (int i = 0; i < 4; ++i)
        #pragma unroll
        for (int j = 0; j < 4; ++j)
          acc[i][j] = __builtin_amdgcn_mfma_f32_16x16x32_bf16(af[i], bfr[j], acc[i][j], 0, 0, 0);
    }
    __syncthreads();
  }
  #pragma unroll
  for (int i = 0; i < 4; ++i)
    #pragma unroll
    for (int j = 0; j < 4; ++j){
      int col = colStart + wn*64 + j*16 + m16;
      float bias = lr_b[col];
      #pragma unroll
      for (int r = 0; r < 4; ++r){
        int row = rowStart + wm*64 + i*16 + quad*4 + r;
        float v = acc[i][j][r] + bias;
        v = v > 0.f ? v : 0.f;
        f_frag[(size_t)row * H_ + col] = f2bf(v);
      }
    }
}

// ---------------- K3: per-batch fused 2-layer attention ----------------
// HP=552: row stride 276 dwords == 20 mod 32 -> 8 distinct bank starts (2-way, free)
__global__ __launch_bounds__(256) void attn_kernel(
    const unsigned short* __restrict__ f_frag,
    const unsigned short* __restrict__ qkvT, const unsigned short* __restrict__ denseT,
    const float* __restrict__ wq_b, const float* __restrict__ wk_b, const float* __restrict__ wv_b,
    const float* __restrict__ dense_b, const float* __restrict__ ln_g, const float* __restrict__ ln_b,
    unsigned short* __restrict__ hsf, float* __restrict__ out_attn){
  const int HP = 552, TP = 40;
  __shared__ __align__(16) unsigned short hs[S_*552];
  __shared__ __align__(16) unsigned short Qs[S_*40];
  __shared__ __align__(16) unsigned short Ks[S_*40];
  __shared__ __align__(16) unsigned short Vt[S_*40];
  __shared__ __align__(16) unsigned short Ps[S_*40];
  __shared__ __align__(16) unsigned short Xs[S_*40];
  __shared__ unsigned long long pmask[S_*8];
  __shared__ unsigned int mz[S_];
  int b = blockIdx.x;
  int tid = threadIdx.x;
  int wave = tid >> 6, lane = tid & 63;
  int m16 = lane & 15, quad = lane >> 4;

  {
    int row = tid >> 3, cc = (tid & 7) * 64;
    const unsigned short* src = f_frag + ((size_t)(b * S_ + row)) * H_ + cc;
    unsigned short* dst = hs + row * HP + cc;
    #pragma unroll
    for (int k = 0; k < 64; k += 8)
      *(uint4*)(dst + k) = *(const uint4*)(src + k);
  }
  if (tid < S_) mz[tid] = 0u;
  __syncthreads();
  {
    int s = tid >> 3, w = tid & 7;
    const unsigned short* hrow = hs + s * HP + w * 64;
    unsigned long long m = 0ull;
    #pragma unroll
    for (int c = 0; c < 64; c += 8){
      short8 hv = *(const short8*)(hrow + c);
      #pragma unroll
      for (int j = 0; j < 8; ++j)
        if ((unsigned short)hv[j] != 0) m |= (1ull << (c + j));
    }
    pmask[s * 8 + w] = m;
  }
  __syncthreads();
  for (int idx = tid; idx < S_*S_; idx += 256){
    int s = idx >> 5, t2 = idx & 31;
    bool inter = false;
    #pragma unroll
    for (int w = 0; w < 8; ++w)
      inter = inter || ((pmask[s*8+w] & pmask[t2*8+w]) != 0ull);
    if (!inter) atomicOr(&mz[s], 1u << t2);
  }
  __syncthreads();

  const float scale = 0.17677669529663687f;
  for (int l = 0; l < L_; ++l){
    {
      int mt = wave >> 1, nt = wave & 1;
      floatx4 aq = {0,0,0,0}, ak = {0,0,0,0}, av = {0,0,0,0};
      const unsigned short* arow = hs + (mt*16 + m16) * HP + quad*8;
      const unsigned short* bq = qkvT + ((size_t)((l*3 + 0)*S_ + nt*16 + m16)) * H_ + quad*8;
      const unsigned short* bk = bq + (size_t)S_ * H_;
      const unsigned short* bv = bk + (size_t)S_ * H_;
      for (int k0 = 0; k0 < H_; k0 += 32){
        short8 a = *(const short8*)(arow + k0);
        aq = __builtin_amdgcn_mfma_f32_16x16x32_bf16(a, *(const short8*)(bq + k0), aq, 0,0,0);
        ak = __builtin_amdgcn_mfma_f32_16x16x32_bf16(a, *(const short8*)(bk + k0), ak, 0,0,0);
        av = __builtin_amdgcn_mfma_f32_16x16x32_bf16(a, *(const short8*)(bv + k0), av, 0,0,0);
      }
      int col = nt*16 + m16;
      float bqs = wq_b[l*DK_ + col], bks = wk_b[l*DK_ + col], bvs = wv_b[l*DK_ + col];
      #pragma unroll
      for (int r = 0; r < 4; ++r){
        int rw = mt*16 + quad*4 + r;
        Qs[rw*TP + col] = f2bf((aq[r] + bqs) * scale);
        Ks[rw*TP + col] = f2bf(ak[r] + bks);
        Vt[col*TP + rw] = f2bf(av[r] + bvs);
      }
    }
    __syncthreads();
    if (wave < 2){
      int mt = wave;
      short8 a  = *(const short8*)(Qs + (mt*16 + m16)*TP + quad*8);
      short8 b0 = *(const short8*)(Ks + m16*TP + quad*8);
      short8 b1 = *(const short8*)(Ks + (16 + m16)*TP + quad*8);
      floatx4 z = {0,0,0,0};
      floatx4 s0 = __builtin_amdgcn_mfma_f32_16x16x32_bf16(a, b0, z, 0,0,0);
      floatx4 s1 = __builtin_amdgcn_mfma_f32_16x16x32_bf16(a, b1, z, 0,0,0);
      #pragma unroll
      for (int r = 0; r < 4; ++r){
        int s = mt*16 + quad*4 + r;
        unsigned int m = mz[s];
        float v0 = ((m >> m16) & 1u) ? -1e9f : s0[r];
        float v1 = ((m >> (16 + m16)) & 1u) ? -1e9f : s1[r];
        float mx = fmaxf(v0, v1);
        #pragma unroll
        for (int d = 1; d < 16; d <<= 1) mx = fmaxf(mx, __shfl_xor(mx, d));
        float e0 = __expf(v0 - mx), e1 = __expf(v1 - mx);
        float sm = e0 + e1;
        #pragma unroll
        for (int d = 1; d < 16; d <<= 1) sm += __shfl_xor(sm, d);
        float inv = 1.f / sm;
        float p0 = e0 * inv, p1 = e1 * inv;
        Ps[s*TP + m16] = f2bf(p0);
        Ps[s*TP + 16 + m16] = f2bf(p1);
        if (l == L_ - 1){
          float* oa = out_attn + ((size_t)b * S_ + s) * S_;
          oa[m16] = p0; oa[16 + m16] = p1;
        }
      }
    }
    __syncthreads();
    {
      int mt = wave >> 1, nt = wave & 1;
      short8 a  = *(const short8*)(Ps + (mt*16 + m16)*TP + quad*8);
      short8 bv = *(const short8*)(Vt + (nt*16 + m16)*TP + quad*8);
      floatx4 z = {0,0,0,0};
      floatx4 x = __builtin_amdgcn_mfma_f32_16x16x32_bf16(a, bv, z, 0,0,0);
      #pragma unroll
      for (int r = 0; r < 4; ++r)
        Xs[(mt*16 + quad*4 + r)*TP + nt*16 + m16] = f2bf(x[r]);
    }
    __syncthreads();
    {
      short8 bx0 = *(const short8*)(Xs + m16*TP + quad*8);
      short8 bx1 = *(const short8*)(Xs + (16 + m16)*TP + quad*8);
      #pragma unroll
      for (int j = 0; j < 8; ++j){
        int dct = wave*8 + j;
        short8 aw = *(const short8*)(denseT + ((size_t)(l*H_ + dct*16 + m16)) * DK_ + quad*8);
        floatx4 z = {0,0,0,0};
        floatx4 d0 = __builtin_amdgcn_mfma_f32_16x16x32_bf16(aw, bx0, z, 0,0,0);
        floatx4 d1 = __builtin_amdgcn_mfma_f32_16x16x32_bf16(aw, bx1, z, 0,0,0);
        int dc0 = dct*16 + quad*4;
        float4 db4 = *(const float4*)(dense_b + l*H_ + dc0);
        const float dbr[4] = {db4.x, db4.y, db4.z, db4.w};
        unsigned short* h0 = hs + m16*HP + dc0;
        unsigned short* h1 = hs + (16 + m16)*HP + dc0;
        unsigned long long u0 = *(unsigned long long*)h0;
        unsigned long long u1 = *(unsigned long long*)h1;
        unsigned long long o0 = 0ull, o1 = 0ull;
        #pragma unroll
        for (int r = 0; r < 4; ++r){
          float hv0 = bf2f((unsigned short)(u0 >> (16*r)));
          float hv1 = bf2f((unsigned short)(u1 >> (16*r)));
          o0 |= (unsigned long long)f2bf(d0[r] + dbr[r] + hv0) << (16*r);
          o1 |= (unsigned long long)f2bf(d1[r] + dbr[r] + hv1) << (16*r);
        }
        *(unsigned long long*)h0 = o0;
        *(unsigned long long*)h1 = o1;
      }
    }
    __syncthreads();
    {
      #pragma unroll
      for (int rr = 0; rr < 8; ++rr){
        int row = wave*8 + rr;
        unsigned short* hrow = hs + row*HP + lane*8;
        short8 hv = *(const short8*)hrow;
        float v[8]; float s1 = 0.f, s2 = 0.f;
        #pragma unroll
        for (int j = 0; j < 8; ++j){ v[j] = bf2f((unsigned short)hv[j]); s1 += v[j]; s2 += v[j]*v[j]; }
        #pragma unroll
        for (int d = 1; d < 64; d <<= 1){ s1 += __shfl_xor(s1, d); s2 += __shfl_xor(s2, d); }
        float mean = s1 * (1.f/512.f);
        float var = s2 * (1.f/512.f) - mean*mean;
        float rs = rsqrtf(var + 1e-6f);
        unsigned short o[8] __attribute__((aligned(16)));
        #pragma unroll
        for (int j = 0; j < 8; ++j){
          int colj = lane*8 + j;
          float nv = (v[j] - mean) * rs * ln_g[l*H_ + colj] + ln_b[l*H_ + colj];
          o[j] = f2bf(nv);
        }
        *(uint4*)hrow = *(const uint4*)o;
      }
    }
    __syncthreads();
  }
  if (tid < 64){
    *(uint4*)(hsf + (size_t)b * H_ + tid*8) = *(const uint4*)(hs + tid*8);
  }
}

// ---------------- K4: f_out = LN(hs0 @ lin_w + lin_b; eps 1e-5) * alpha ----------------
__global__ __launch_bounds__(256) void final_kernel(
    const unsigned short* __restrict__ hsf, const unsigned short* __restrict__ lin_wT,
    const float* __restrict__ lin_b, const float* __restrict__ norm_g, const float* __restrict__ norm_b,
    const float* __restrict__ alpha, float* __restrict__ out_f){
  const int HP = 552;
  __shared__ __align__(16) unsigned short hsb[32*552];
  int blk = blockIdx.x;
  int tid = threadIdx.x;
  int wave = tid >> 6, lane = tid & 63;
  int m16 = lane & 15, quad = lane >> 4;
  {
    int row = tid >> 3, cc = (tid & 7) * 64;
    const unsigned short* src = hsf + ((size_t)(blk*32 + row)) * H_ + cc;
    unsigned short* dst = hsb + row*HP + cc;
    #pragma unroll
    for (int k = 0; k < 64; k += 8)
      *(uint4*)(dst + k) = *(const uint4*)(src + k);
  }
  __syncthreads();
  floatx4 acc[2][8];
  #pragma unroll
  for (int mt = 0; mt < 2; ++mt)
    #pragma unroll
    for (int j = 0; j < 8; ++j) acc[mt][j] = (floatx4){0.f,0.f,0.f,0.f};
  for (int k0 = 0; k0 < H_; k0 += 32){
    short8 a0 = *(const short8*)(hsb + m16*HP + k0 + quad*8);
    short8 a1 = *(const short8*)(hsb + (16 + m16)*HP + k0 + quad*8);
    #pragma unroll
    for (int j = 0; j < 8; ++j){
      int n = (wave*8 + j)*16 + m16;
      short8 bw = *(const short8*)(lin_wT + (size_t)n * H_ + k0 + quad*8);
      acc[0][j] = __builtin_amdgcn_mfma_f32_16x16x32_bf16(a0, bw, acc[0][j], 0,0,0);
      acc[1][j] = __builtin_amdgcn_mfma_f32_16x16x32_bf16(a1, bw, acc[1][j], 0,0,0);
    }
  }
  __syncthreads();
  #pragma unroll
  for (int mt = 0; mt < 2; ++mt)
    #pragma unroll
    for (int j = 0; j < 8; ++j){
      int col = (wave*8 + j)*16 + m16;
      float lb = lin_b[col];
      #pragma unroll
      for (int r = 0; r < 4; ++r){
        int row = mt*16 + quad*4 + r;
        hsb[row*HP + col] = f2bf(acc[mt][j][r] + lb);
      }
    }
  __syncthreads();
  float al = alpha[0];
  #pragma unroll
  for (int rr = 0; rr < 8; ++rr){
    int row = wave*8 + rr;
    const unsigned short* hrow = hsb + row*HP + lane*8;
    short8 hv = *(const short8*)hrow;
    float v[8]; float s1 = 0.f, s2 = 0.f;
    #pragma unroll
    for (int j = 0; j < 8; ++j){ v[j] = bf2f((unsigned short)hv[j]); s1 += v[j]; s2 += v[j]*v[j]; }
    #pragma unroll
    for (int d = 1; d < 64; d <<= 1){ s1 += __shfl_xor(s1, d); s2 += __shfl_xor(s2, d); }
    float mean = s1 * (1.f/512.f);
    float var = s2 * (1.f/512.f) - mean*mean;
    float rs = rsqrtf(var + 1e-5f);
    float o[8];
    #pragma unroll
    for (int j = 0; j < 8; ++j){
      int colj = lane*8 + j;
      o[j] = ((v[j] - mean) * rs * norm_g[colj] + norm_b[colj]) * al;
    }
    float* op = out_f + ((size_t)(blk*32 + row)) * H_ + lane*8;
    float4 f0 = {o[0], o[1], o[2], o[3]};
    float4 f1 = {o[4], o[5], o[6], o[7]};
    *(float4*)op = f0;
    *(float4*)(op + 4) = f1;
  }
}

extern "C" void kernel_launch(void* const* d_in, const int* in_sizes, int n_in,
                              void* d_out, int out_size, void* d_ws, size_t ws_size,
                              hipStream_t stream){
  const float* f_atom  = (const float*)d_in[0];
  const float* f_group = (const float*)d_in[1];
  const float* fg      = (const float*)d_in[2];
  const float* alpha   = (const float*)d_in[3];
  const float* lr_w    = (const float*)d_in[4];
  const float* lr_b    = (const float*)d_in[5];
  const float* wq_w    = (const float*)d_in[6];
  const float* wq_b    = (const float*)d_in[7];
  const float* wk_w    = (const float*)d_in[8];
  const float* wk_b    = (const float*)d_in[9];
  const float* wv_w    = (const float*)d_in[10];
  const float* wv_b    = (const float*)d_in[11];
  const float* dense_w = (const float*)d_in[12];
  const float* dense_b = (const float*)d_in[13];
  const float* ln_g    = (const float*)d_in[14];
  const float* ln_b    = (const float*)d_in[15];
  const float* lin_w   = (const float*)d_in[16];
  const float* lin_b   = (const float*)d_in[17];
  const float* norm_g  = (const float*)d_in[18];
  const float* norm_b  = (const float*)d_in[19];
  const int*   mapping = (const int*)d_in[20];

  unsigned short* brics  = (unsigned short*)d_ws;
  unsigned short* f_frag = brics  + (size_t)32768 * 1536;
  unsigned short* lr_wT  = f_frag + (size_t)32768 * 512;
  unsigned short* qkvT   = lr_wT  + (size_t)512 * 1536;
  unsigned short* denseT = qkvT   + (size_t)2*3*32*512;
  unsigned short* lin_wT = denseT + (size_t)2*512*32;
  unsigned short* hsf    = lin_wT + (size_t)512*512;

  float* out_f    = (float*)d_out;
  float* out_attn = out_f + (size_t)B_ * H_;

  prep_and_build<<<8960, 512, 0, stream>>>(f_atom, f_group, fg, mapping,
                                           lr_w, lin_w, wq_w, wk_w, wv_w, dense_w,
                                           brics, lr_wT, lin_wT, qkvT, denseT);
  gemm_frag<<<(32768/128) * (512/128), 256, 0, stream>>>(brics, lr_wT, lr_b, f_frag);
  attn_kernel<<<B_, 256, 0, stream>>>(f_frag, qkvT, denseT, wq_b, wk_b, wv_b,
                                      dense_b, ln_g, ln_b, hsf, out_attn);
  final_kernel<<<B_/32, 256, 0, stream>>>(hsf, lin_wT, lin_b, norm_g, norm_b, alpha, out_f);
}